// Round 17
// baseline (104.372 us; speedup 1.0000x reference)
//
#include <hip/hip_runtime.h>
#include <math.h>

#define DD 16
#define KK 1024

typedef float f2 __attribute__((ext_vector_type(2)));

// ---- workspace layout (doubles) ----
#define WS_A    0
#define WS_ASQ  16384
#define WS_OMC  17408
#define WS_B2   17424
#define WS_E2   17440
#define WS_MN   17456
#define WS_MX   17472
#define WS_SCL  17488
#define WS_DIM  17504
#define WS_E1   17520
#define WS_BASE 17536
#define WS_TOTD 17537
#define WS_NEED_BYTES (WS_TOTD * 8)

__device__ __forceinline__ double xformD(double rv, double mn, double scl) {
  double t = rv / (1.0 + fabs(rv));
  return (t + 1.0) * 0.5 * scl + mn;
}
__device__ __forceinline__ float xformF(float v, float mn, float mx) {
  return (v / (1.f + fabsf(v)) + 1.f) * 0.5f * (mx - mn) + mn;
}

// =============== kernel A: precompute f64 tables into ws (proven) ===============
__global__ __launch_bounds__(256) void vor_pre(
    const float* __restrict__ an1_w, const float* __restrict__ an2_w,
    const float* __restrict__ an2_b, const float* __restrict__ shift_c,
    const float* __restrict__ anchor_raw,
    const float* __restrict__ box_min, const float* __restrict__ box_max,
    const float* __restrict__ mlogits, double* __restrict__ ws)
{
  __shared__ double redD[16];
  const int tid = threadIdx.x;
  const int blk = blockIdx.x;

  if (blk == 0 && tid < DD) {
    double w1 = (double)an1_w[tid], w2 = (double)an2_w[tid];
    double sgc = 1.0 / (1.0 + exp(-(double)shift_c[tid]));
    double c = sgc * 0.98 + 0.01;
    double mn = (double)box_min[tid], mx = (double)box_max[tid];
    ws[WS_OMC + tid] = 1.0 - c;
    ws[WS_B2  + tid] = (double)an2_b[tid];
    ws[WS_E2  + tid] = exp(w2);
    ws[WS_MN  + tid] = mn;
    ws[WS_MX  + tid] = mx;
    ws[WS_SCL + tid] = mx - mn;
    ws[WS_E1  + tid] = exp(w1);
    ws[WS_DIM + tid] = -w1 - log(mx - mn) - log1p(-c) - w2;
  }
  const int j0 = blk * 64;
  for (int e = tid; e < 64 * DD; e += 256) {
    int j = j0 + (e >> 4), d = e & 15;
    double mn = (double)box_min[d];
    double scl = (double)box_max[d] - mn;
    ws[WS_A + (size_t)j * DD + d] = xformD((double)anchor_raw[j * DD + d], mn, scl);
  }
  __syncthreads();
  for (int j = j0 + tid; j < j0 + 64; j += 256) {
    double s = 0.0;
    #pragma unroll
    for (int d = 0; d < DD; ++d) { double a = ws[WS_A + (size_t)j * DD + d]; s = fma(a, a, s); }
    ws[WS_ASQ + j] = s;
  }
  if (blk != 0) return;
  float lm = -3.4e38f;
  for (int i = tid; i < KK; i += 256) lm = fmaxf(lm, mlogits[i]);
  #pragma unroll
  for (int o = 32; o > 0; o >>= 1) lm = fmaxf(lm, __shfl_xor(lm, o));
  if ((tid & 63) == 0) redD[tid >> 6] = (double)lm;
  __syncthreads();
  float gmax = (float)fmax(fmax(redD[0], redD[1]), fmax(redD[2], redD[3]));
  double lsum = 0.0;
  for (int i = tid; i < KK; i += 256) lsum += exp((double)mlogits[i] - (double)gmax);
  #pragma unroll
  for (int o = 32; o > 0; o >>= 1) lsum += __shfl_xor(lsum, o);
  if ((tid & 63) == 0) redD[4 + (tid >> 6)] = lsum;
  __syncthreads();
  if (tid == 0) {
    double lse = (double)gmax + log(redD[4] + redD[5] + redD[6] + redD[7]);
    double b = (double)DD * (log(0.98) + log(1.0 + 2.0 * (0.01 / 0.98)));
    #pragma unroll
    for (int d = 0; d < DD; ++d) b += ws[WS_DIM + d];
    ws[WS_BASE] = b + lse;
  }
}

// =============== kernel B: row-paired pk sweeps (2 rows per thread) ===============
#define NT2 1024
#define RPB2 128
#define NSL 16            // 16 slices of 64 j
#define JSL 64

__global__ __launch_bounds__(NT2, 4) void vor7(
    const float* __restrict__ x_in, const float* __restrict__ logp_in,
    const float* __restrict__ an1_b,
    const float* __restrict__ mlogits, const double* __restrict__ ws,
    float* __restrict__ out, int Brows)
{
  __shared__ __align__(16) float sAp[KK][DD];  // 64 KB anchors, pair-permuted {0,8,1,9,...}
  __shared__ float  sAsqH[KK];                 // 4 KB
  __shared__ double sX4D[DD][RPB2];            // 16 KB f64 x4
  __shared__ float  sLT[DD][RPB2];             // 8 KB lsig terms
  __shared__ double sD2[NSL][RPB2];            // 16 KB refined d2 per (slice,row)
  __shared__ int    sJJ[NSL][RPB2];            // 8 KB refined j
  __shared__ float  sRat[NSL][RPB2];           // 8 KB ratio cand per (slice,row)
  __shared__ float  sOmcF[DD], sB2F[DD], sE2F[DD], sMnF[DD], sMxF[DD];

  const int tid  = threadIdx.x;
  const int w    = tid >> 6;        // slice 0..15
  const int lane = tid & 63;
  const int r0   = lane, r1 = lane + 64;
  const int row0 = blockIdx.x * RPB2 + r0;
  const int row1 = blockIdx.x * RPB2 + r1;
  const size_t coreEnd = (size_t)Brows * (DD + 1);

  if (tid < DD) {
    sOmcF[tid] = (float)ws[WS_OMC + tid];
    sB2F[tid]  = (float)ws[WS_B2 + tid];
    sE2F[tid]  = (float)ws[WS_E2 + tid];
    sMnF[tid]  = (float)ws[WS_MN + tid];
    sMxF[tid]  = (float)ws[WS_MX + tid];
  }
  // stage anchors pair-permuted from f64 ws (proven provenance)
  for (int e = tid; e < KK * DD; e += NT2) {
    int j = e >> 4, d = e & 15;
    float v = (float)ws[WS_A + (size_t)j * DD + d];
    int pos = (d < 8) ? (2 * d) : (2 * (d - 8) + 1);
    sAp[j][pos] = v;
  }
  // f64 x4 chain distributed (2 elems/thread)
  {
    const double A = 0.01, EPSB = 0.01 / 0.98;
    const double SPAN = 1.0 + 2.0 * EPSB;
    const float* xb = x_in + (size_t)blockIdx.x * RPB2 * DD;
    for (int e = tid; e < RPB2 * DD; e += NT2) {
      int rr = e >> 4, d = e & 15;
      double y1 = ((double)xb[e] + (double)an1_b[d]) * ws[WS_E1 + d];
      double sg = 1.0 / (1.0 + exp(-y1));
      double x2 = (sg - A) / (1.0 - 2.0 * A);
      double x3 = (x2 + EPSB) / SPAN;
      double x4 = x3 * ws[WS_SCL + d] + ws[WS_MN + d];
      sX4D[d][rr] = x4;
      double ay = fabs(y1);
      sLT[d][rr] = (float)(ay + 2.0 * log1p(exp(-ay)));
    }
  }
  // zero this block's f32 mask stripe
  {
    float4* mz = (float4*)(out + coreEnd + (size_t)blockIdx.x * RPB2 * KK);
    #pragma unroll 4
    for (int i = tid; i < RPB2 * KK / 4; i += NT2)
      mz[i] = make_float4(0.f, 0.f, 0.f, 0.f);
  }
  __syncthreads();     // sAp, sX4D, sLT ready

  // asqH: natural-order f32 fmaf chain (bit-identical provenance) from permuted storage
  for (int j = tid; j < KK; j += NT2) {
    float a[DD];
    #pragma unroll
    for (int i = 0; i < 8; ++i) { a[i] = sAp[j][2 * i]; a[i + 8] = sAp[j][2 * i + 1]; }
    float acc = 0.f;
    #pragma unroll
    for (int d = 0; d < DD; ++d) acc = fmaf(a[d], a[d], acc);
    sAsqH[j] = 0.5f * acc;
  }

  float x4f0[DD], x4f1[DD];
  #pragma unroll
  for (int d = 0; d < DD; ++d) { x4f0[d] = (float)sX4D[d][r0]; x4f1[d] = (float)sX4D[d][r1]; }
  f2 xp0[8], xp1[8];
  #pragma unroll
  for (int i = 0; i < 8; ++i) {
    xp0[i] = (f2){x4f0[i], x4f0[i + 8]};
    xp1[i] = (f2){x4f1[i], x4f1[i + 8]};
  }
  __syncthreads();     // sAsqH ready

  // ---- sweep 1 (pk, 2 rows per anchor load): top-2 per row over 64-j slice ----
  const int jlo = w * JSL, jhi = jlo + JSL;
  float m1_0 = -3.4e38f, m2_0 = -3.4e38f; int j1_0 = jlo, j2_0 = jlo;
  float m1_1 = -3.4e38f, m2_1 = -3.4e38f; int j1_1 = jlo, j2_1 = jlo;
  #pragma unroll 2
  for (int j = jlo; j < jhi; ++j) {
    const float4* ar = (const float4*)&sAp[j][0];
    float4 A0 = ar[0], A1 = ar[1], A2 = ar[2], A3 = ar[3];
    f2 p0 = (f2){A0.x, A0.y}, p1 = (f2){A0.z, A0.w};
    f2 p2 = (f2){A1.x, A1.y}, p3 = (f2){A1.z, A1.w};
    f2 p4 = (f2){A2.x, A2.y}, p5 = (f2){A2.z, A2.w};
    f2 p6 = (f2){A3.x, A3.y}, p7 = (f2){A3.z, A3.w};
    float nq = -sAsqH[j];
    f2 a0 = (f2){nq, 0.f}, a1 = (f2){nq, 0.f};
    a0 = __builtin_elementwise_fma(xp0[0], p0, a0); a1 = __builtin_elementwise_fma(xp1[0], p0, a1);
    a0 = __builtin_elementwise_fma(xp0[1], p1, a0); a1 = __builtin_elementwise_fma(xp1[1], p1, a1);
    a0 = __builtin_elementwise_fma(xp0[2], p2, a0); a1 = __builtin_elementwise_fma(xp1[2], p2, a1);
    a0 = __builtin_elementwise_fma(xp0[3], p3, a0); a1 = __builtin_elementwise_fma(xp1[3], p3, a1);
    a0 = __builtin_elementwise_fma(xp0[4], p4, a0); a1 = __builtin_elementwise_fma(xp1[4], p4, a1);
    a0 = __builtin_elementwise_fma(xp0[5], p5, a0); a1 = __builtin_elementwise_fma(xp1[5], p5, a1);
    a0 = __builtin_elementwise_fma(xp0[6], p6, a0); a1 = __builtin_elementwise_fma(xp1[6], p6, a1);
    a0 = __builtin_elementwise_fma(xp0[7], p7, a0); a1 = __builtin_elementwise_fma(xp1[7], p7, a1);
    float s0 = a0.x + a0.y, s1 = a1.x + a1.y;
    bool g1 = s0 > m1_0, g2 = s0 > m2_0;
    m2_0 = g1 ? m1_0 : (g2 ? s0 : m2_0);
    j2_0 = g1 ? j1_0 : (g2 ? j : j2_0);
    m1_0 = g1 ? s0 : m1_0;
    j1_0 = g1 ? j : j1_0;
    bool h1b = s1 > m1_1, h2b = s1 > m2_1;
    m2_1 = h1b ? m1_1 : (h2b ? s1 : m2_1);
    j2_1 = h1b ? j1_1 : (h2b ? j : j2_1);
    m1_1 = h1b ? s1 : m1_1;
    j1_1 = h1b ? j : j1_1;
  }

  // ---- per-wave f64 refine: 2 candidates for each of 2 rows ----
  {
    double bD = 1e300; int bk = 0x7fffffff;
    #pragma unroll
    for (int t = 0; t < 2; ++t) {
      int j = t ? j2_0 : j1_0;
      const double* aj = ws + WS_A + (size_t)j * DD;
      double dot = 0.0;
      #pragma unroll
      for (int d = 0; d < DD; ++d) dot = fma(sX4D[d][r0], aj[d], dot);
      double d2 = ws[WS_ASQ + j] - 2.0 * dot;
      if (d2 < bD || (d2 == bD && j < bk)) { bD = d2; bk = j; }
    }
    sD2[w][r0] = bD; sJJ[w][r0] = bk;
  }
  {
    double bD = 1e300; int bk = 0x7fffffff;
    #pragma unroll
    for (int t = 0; t < 2; ++t) {
      int j = t ? j2_1 : j1_1;
      const double* aj = ws + WS_A + (size_t)j * DD;
      double dot = 0.0;
      #pragma unroll
      for (int d = 0; d < DD; ++d) dot = fma(sX4D[d][r1], aj[d], dot);
      double d2 = ws[WS_ASQ + j] - 2.0 * dot;
      if (d2 < bD || (d2 == bD && j < bk)) { bD = d2; bk = j; }
    }
    sD2[w][r1] = bD; sJJ[w][r1] = bk;
  }
  __syncthreads();

  // combine k per row (same data read by all waves -> identical result)
  int k0 = 0x7fffffff, k1 = 0x7fffffff;
  {
    double kb0 = 1e300, kb1 = 1e300;
    #pragma unroll
    for (int ss = 0; ss < NSL; ++ss) {
      double d0 = sD2[ss][r0]; int jj0 = sJJ[ss][r0];
      if (d0 < kb0 || (d0 == kb0 && jj0 < k0)) { kb0 = d0; k0 = jj0; }
      double d1 = sD2[ss][r1]; int jj1 = sJJ[ss][r1];
      if (d1 < kb1 || (d1 == kb1 && jj1 < k1)) { kb1 = d1; k1 = jj1; }
    }
  }

  // ---- per-row shift (f32, bit-identical chains) ----
  float akf0[DD], akf1[DD];
  {
    const float4* ap = (const float4*)&sAp[k0][0];
    float4 K0 = ap[0], K1 = ap[1], K2 = ap[2], K3 = ap[3];
    akf0[0]=K0.x; akf0[8]=K0.y; akf0[1]=K0.z; akf0[9]=K0.w;
    akf0[2]=K1.x; akf0[10]=K1.y; akf0[3]=K1.z; akf0[11]=K1.w;
    akf0[4]=K2.x; akf0[12]=K2.y; akf0[5]=K2.z; akf0[13]=K2.w;
    akf0[6]=K3.x; akf0[14]=K3.y; akf0[7]=K3.z; akf0[15]=K3.w;
  }
  {
    const float4* ap = (const float4*)&sAp[k1][0];
    float4 K0 = ap[0], K1 = ap[1], K2 = ap[2], K3 = ap[3];
    akf1[0]=K0.x; akf1[8]=K0.y; akf1[1]=K0.z; akf1[9]=K0.w;
    akf1[2]=K1.x; akf1[10]=K1.y; akf1[3]=K1.z; akf1[11]=K1.w;
    akf1[4]=K2.x; akf1[12]=K2.y; akf1[5]=K2.z; akf1[13]=K2.w;
    akf1[6]=K3.x; akf1[14]=K3.y; akf1[7]=K3.z; akf1[15]=K3.w;
  }
  float dxf0[DD], dxf1[DD];
  float r2_0 = 0.f, dk_0 = 0.f, r2_1 = 0.f, dk_1 = 0.f;
  #pragma unroll
  for (int d = 0; d < DD; ++d) {
    float dx0 = sOmcF[d] * (x4f0[d] - akf0[d]);
    dxf0[d] = dx0;
    r2_0 = fmaf(dx0, dx0, r2_0);
    dk_0 = fmaf(dx0, akf0[d], dk_0);
    float dx1 = sOmcF[d] * (x4f1[d] - akf1[d]);
    dxf1[d] = dx1;
    r2_1 = fmaf(dx1, dx1, r2_1);
    dk_1 = fmaf(dx1, akf1[d], dk_1);
  }
  const float rf0 = sqrtf(r2_0), rr0 = fmaxf(rf0, 1e-12f), sc0 = rf0 / rr0, ep0 = 1e-12f * rf0;
  const float rf1 = sqrtf(r2_1), rr1 = fmaxf(rf1, 1e-12f), sc1 = rf1 / rr1, ep1 = 1e-12f * rf1;
  const float ah0 = sAsqH[k0], ah1 = sAsqH[k1];

  f2 dxp0[8], dxp1[8], nk0[8], nk1[8];
  #pragma unroll
  for (int i = 0; i < 8; ++i) {
    dxp0[i] = (f2){dxf0[i], dxf0[i + 8]};
    dxp1[i] = (f2){dxf1[i], dxf1[i + 8]};
    nk0[i]  = (f2){-akf0[i], -akf0[i + 8]};
    nk1[i]  = (f2){-akf1[i], -akf1[i + 8]};
  }

  // ---- sweep 2 (pk, 2 rows per anchor load): best q/h per row ----
  float q1_0 = 0.f, h1_0 = 1.f, q1_1 = 0.f, h1_1 = 1.f;
  for (int j = jlo; j < jhi; ++j) {
    const float4* ar = (const float4*)&sAp[j][0];
    float4 A0 = ar[0], A1 = ar[1], A2 = ar[2], A3 = ar[3];
    f2 p0 = (f2){A0.x, A0.y}, p1 = (f2){A0.z, A0.w};
    f2 p2 = (f2){A1.x, A1.y}, p3 = (f2){A1.z, A1.w};
    f2 p4 = (f2){A2.x, A2.y}, p5 = (f2){A2.z, A2.w};
    f2 p6 = (f2){A3.x, A3.y}, p7 = (f2){A3.z, A3.w};
    float aj = sAsqH[j];
    f2 q0 = (f2){-dk_0, 0.f}, h0 = (f2){ah0 + aj, 0.f};
    f2 q1v = (f2){-dk_1, 0.f}, h1v = (f2){ah1 + aj, 0.f};
    q0 = __builtin_elementwise_fma(dxp0[0], p0, q0); h0 = __builtin_elementwise_fma(nk0[0], p0, h0);
    q1v = __builtin_elementwise_fma(dxp1[0], p0, q1v); h1v = __builtin_elementwise_fma(nk1[0], p0, h1v);
    q0 = __builtin_elementwise_fma(dxp0[1], p1, q0); h0 = __builtin_elementwise_fma(nk0[1], p1, h0);
    q1v = __builtin_elementwise_fma(dxp1[1], p1, q1v); h1v = __builtin_elementwise_fma(nk1[1], p1, h1v);
    q0 = __builtin_elementwise_fma(dxp0[2], p2, q0); h0 = __builtin_elementwise_fma(nk0[2], p2, h0);
    q1v = __builtin_elementwise_fma(dxp1[2], p2, q1v); h1v = __builtin_elementwise_fma(nk1[2], p2, h1v);
    q0 = __builtin_elementwise_fma(dxp0[3], p3, q0); h0 = __builtin_elementwise_fma(nk0[3], p3, h0);
    q1v = __builtin_elementwise_fma(dxp1[3], p3, q1v); h1v = __builtin_elementwise_fma(nk1[3], p3, h1v);
    q0 = __builtin_elementwise_fma(dxp0[4], p4, q0); h0 = __builtin_elementwise_fma(nk0[4], p4, h0);
    q1v = __builtin_elementwise_fma(dxp1[4], p4, q1v); h1v = __builtin_elementwise_fma(nk1[4], p4, h1v);
    q0 = __builtin_elementwise_fma(dxp0[5], p5, q0); h0 = __builtin_elementwise_fma(nk0[5], p5, h0);
    q1v = __builtin_elementwise_fma(dxp1[5], p5, q1v); h1v = __builtin_elementwise_fma(nk1[5], p5, h1v);
    q0 = __builtin_elementwise_fma(dxp0[6], p6, q0); h0 = __builtin_elementwise_fma(nk0[6], p6, h0);
    q1v = __builtin_elementwise_fma(dxp1[6], p6, q1v); h1v = __builtin_elementwise_fma(nk1[6], p6, h1v);
    q0 = __builtin_elementwise_fma(dxp0[7], p7, q0); h0 = __builtin_elementwise_fma(nk0[7], p7, h0);
    q1v = __builtin_elementwise_fma(dxp1[7], p7, q1v); h1v = __builtin_elementwise_fma(nk1[7], p7, h1v);
    {
      float q = q0.x + q0.y, h = h0.x + h0.y;
      bool upd = (j != k0) & (q > ep0) & (q * h1_0 > q1_0 * h);
      q1_0 = upd ? q : q1_0;
      h1_0 = upd ? h : h1_0;
    }
    {
      float q = q1v.x + q1v.y, h = h1v.x + h1v.y;
      bool upd = (j != k1) & (q > ep1) & (q * h1_1 > q1_1 * h);
      q1_1 = upd ? q : q1_1;
      h1_1 = upd ? h : h1_1;
    }
  }
  sRat[w][r0] = sc0 * (q1_0 / h1_0);
  sRat[w][r1] = sc1 * (q1_1 / h1_1);
  __syncthreads();

  // ---- epilogue (wave 0): both rows per thread ----
  if (w == 0) {
    // row 0
    {
      float ratio = rf0 * 1e-9f;
      #pragma unroll
      for (int ss = 0; ss < NSL; ++ss) ratio = fmaxf(ratio, sRat[ss][r0]);
      #pragma unroll
      for (int d = 0; d < DD; ++d) {
        float uf = dxf0[d] / rr0;
        if (uf > 1e-12f)        ratio = fmaxf(ratio, rf0 * uf / (sMxF[d] - akf0[d]));
        else if (uf < -1e-12f)  ratio = fmaxf(ratio, rf0 * uf / (sMnF[d] - akf0[d]));
      }
      float sS = 1.0f / (1.0f - ratio);
      float xo[DD];
      float lsig = 0.f;
      #pragma unroll
      for (int d = 0; d < DD; ++d) {
        xo[d] = (dxf0[d] * sS + sB2F[d]) * sE2F[d];
        lsig += sLT[d][r0];
      }
      float4* xp = (float4*)(out + (size_t)row0 * DD);
      xp[0] = make_float4(xo[0], xo[1], xo[2], xo[3]);
      xp[1] = make_float4(xo[4], xo[5], xo[6], xo[7]);
      xp[2] = make_float4(xo[8], xo[9], xo[10], xo[11]);
      xp[3] = make_float4(xo[12], xo[13], xo[14], xo[15]);
      double lp = (double)logp_in[row0] + ws[WS_BASE] + (double)lsig
                + 17.0 * log1p(-(double)ratio)
                - (double)mlogits[k0];
      out[(size_t)Brows * DD + row0] = (float)lp;
      out[coreEnd + (size_t)row0 * KK + k0] = 1.0f;
    }
    // row 1
    {
      float ratio = rf1 * 1e-9f;
      #pragma unroll
      for (int ss = 0; ss < NSL; ++ss) ratio = fmaxf(ratio, sRat[ss][r1]);
      #pragma unroll
      for (int d = 0; d < DD; ++d) {
        float uf = dxf1[d] / rr1;
        if (uf > 1e-12f)        ratio = fmaxf(ratio, rf1 * uf / (sMxF[d] - akf1[d]));
        else if (uf < -1e-12f)  ratio = fmaxf(ratio, rf1 * uf / (sMnF[d] - akf1[d]));
      }
      float sS = 1.0f / (1.0f - ratio);
      float xo[DD];
      float lsig = 0.f;
      #pragma unroll
      for (int d = 0; d < DD; ++d) {
        xo[d] = (dxf1[d] * sS + sB2F[d]) * sE2F[d];
        lsig += sLT[d][r1];
      }
      float4* xp = (float4*)(out + (size_t)row1 * DD);
      xp[0] = make_float4(xo[0], xo[1], xo[2], xo[3]);
      xp[1] = make_float4(xo[4], xo[5], xo[6], xo[7]);
      xp[2] = make_float4(xo[8], xo[9], xo[10], xo[11]);
      xp[3] = make_float4(xo[12], xo[13], xo[14], xo[15]);
      double lp = (double)logp_in[row1] + ws[WS_BASE] + (double)lsig
                + 17.0 * log1p(-(double)ratio)
                - (double)mlogits[k1];
      out[(size_t)Brows * DD + row1] = (float)lp;
      out[coreEnd + (size_t)row1 * KK + k1] = 1.0f;
    }
  }
}

// =============== fallback: round-6 green kernel (unchanged) ===============
#define NT 256
#define RPB 64
#define SLC4 4
#define JSL4 (KK / SLC4)

__global__ __launch_bounds__(NT, 2) void vor_green(
    const float* __restrict__ x_in, const float* __restrict__ logp_in,
    const float* __restrict__ an1_w, const float* __restrict__ an1_b,
    const float* __restrict__ an2_w, const float* __restrict__ an2_b,
    const float* __restrict__ shift_c, const float* __restrict__ anchor_raw,
    const float* __restrict__ box_min, const float* __restrict__ box_max,
    const float* __restrict__ mlogits,
    float* __restrict__ out, int Brows)
{
  __shared__ __align__(16) float sA[KK][DD];
  __shared__ float  sAsqH[KK];
  __shared__ float  sX4T[DD][RPB];
  __shared__ int    sPj1[SLC4][RPB], sPj2[SLC4][RPB];
  __shared__ int    sRI1[SLC4][RPB], sRI2[SLC4][RPB];
  __shared__ double sPartD[8];
  __shared__ double sE1D[DD], sB1D[DD], sOmcD[DD], sB2D[DD], sE2D[DD];
  __shared__ double sMnD[DD], sMxD[DD], sSclD[DD], sDimD[DD];
  __shared__ double sBaseD;
  __shared__ int    sKidx[RPB];

  const int tid  = threadIdx.x;
  const int sl   = tid >> 6;
  const int lane = tid & 63;
  const int row  = blockIdx.x * RPB + lane;
  const size_t coreEnd = (size_t)Brows * (DD + 1);

  for (int e = tid; e < KK * DD / 4; e += NT) {
    float4 raw = ((const float4*)anchor_raw)[e];
    float4 bmn = ((const float4*)box_min)[e & 3];
    float4 bmx = ((const float4*)box_max)[e & 3];
    float4 o;
    o.x = xformF(raw.x, bmn.x, bmx.x);
    o.y = xformF(raw.y, bmn.y, bmx.y);
    o.z = xformF(raw.z, bmn.z, bmx.z);
    o.w = xformF(raw.w, bmn.w, bmx.w);
    ((float4*)sA)[e] = o;
  }
  if (tid < DD) {
    double w1 = (double)an1_w[tid];
    sE1D[tid] = exp(w1);
    sB1D[tid] = (double)an1_b[tid];
    double sgc = 1.0 / (1.0 + exp(-(double)shift_c[tid]));
    double c = sgc * 0.98 + 0.01;
    sOmcD[tid] = 1.0 - c;
    double mn = (double)box_min[tid], mx = (double)box_max[tid];
    sMnD[tid] = mn; sMxD[tid] = mx; sSclD[tid] = mx - mn;
    double w2 = (double)an2_w[tid];
    sE2D[tid] = exp(w2);
    sB2D[tid] = (double)an2_b[tid];
    sDimD[tid] = -w1 - log(mx - mn) - log1p(-c) - w2;
  }
  __syncthreads();

  for (int j = tid; j < KK; j += NT) {
    float acc = 0.f;
    #pragma unroll
    for (int d = 0; d < DD; ++d) { float a = sA[j][d]; acc = fmaf(a, a, acc); }
    sAsqH[j] = 0.5f * acc;
  }

  float lm = -3.4e38f;
  for (int i = tid; i < KK; i += NT) lm = fmaxf(lm, mlogits[i]);
  #pragma unroll
  for (int o = 32; o > 0; o >>= 1) lm = fmaxf(lm, __shfl_xor(lm, o));
  if (lane == 0) sPartD[sl] = (double)lm;
  __syncthreads();
  float gmax = (float)fmax(fmax(sPartD[0], sPartD[1]), fmax(sPartD[2], sPartD[3]));
  double lsum = 0.0;
  for (int i = tid; i < KK; i += NT) lsum += exp((double)mlogits[i] - (double)gmax);
  #pragma unroll
  for (int o = 32; o > 0; o >>= 1) lsum += __shfl_xor(lsum, o);
  if (lane == 0) sPartD[4 + sl] = lsum;
  __syncthreads();
  if (tid == 0) {
    double lse = (double)gmax + log(sPartD[4] + sPartD[5] + sPartD[6] + sPartD[7]);
    double b = (double)DD * (log(0.98) + log(1.0 + 2.0 * (0.01 / 0.98)));
    #pragma unroll
    for (int d = 0; d < DD; ++d) b += sDimD[d];
    sBaseD = b + lse;
  }

  double x4d[DD];
  double lsigD = 0.0;
  if (sl == 0) {
    const double A = 0.01, EPSB = 0.01 / 0.98;
    const double SPAN = 1.0 + 2.0 * EPSB;
    const float* xr = x_in + (size_t)row * DD;
    #pragma unroll
    for (int d = 0; d < DD; ++d) {
      double y1 = ((double)xr[d] + sB1D[d]) * sE1D[d];
      double sg = 1.0 / (1.0 + exp(-y1));
      double x2 = (sg - A) / (1.0 - 2.0 * A);
      double x3 = (x2 + EPSB) / SPAN;
      double x4 = x3 * sSclD[d] + sMnD[d];
      x4d[d] = x4;
      sX4T[d][lane] = (float)x4;
      double ay = fabs(y1);
      lsigD += ay + 2.0 * log1p(exp(-ay));
    }
  }
  {
    float4* mz = (float4*)(out + coreEnd + (size_t)blockIdx.x * RPB * KK);
    #pragma unroll 4
    for (int i = tid; i < RPB * KK / 4; i += NT)
      mz[i] = make_float4(0.f, 0.f, 0.f, 0.f);
  }
  __syncthreads();

  float x4f[DD];
  #pragma unroll
  for (int d = 0; d < DD; ++d) x4f[d] = sX4T[d][lane];

  float m1 = -3.4e38f, m2v = -3.4e38f;
  int j1 = 0x7fffffff, j2v = 0x7fffffff;
  const int jlo = sl * JSL4, jhi = jlo + JSL4;
  #pragma unroll 2
  for (int j = jlo; j < jhi; ++j) {
    float acc = -sAsqH[j];
    const float4* ar = (const float4*)&sA[j][0];
    #pragma unroll
    for (int dq = 0; dq < 4; ++dq) {
      float4 a4 = ar[dq];
      acc = fmaf(x4f[4 * dq + 0], a4.x, acc);
      acc = fmaf(x4f[4 * dq + 1], a4.y, acc);
      acc = fmaf(x4f[4 * dq + 2], a4.z, acc);
      acc = fmaf(x4f[4 * dq + 3], a4.w, acc);
    }
    bool gt1 = acc > m1;
    bool gt2 = acc > m2v;
    m2v = gt1 ? m1 : (gt2 ? acc : m2v);
    j2v = gt1 ? j1 : (gt2 ? j : j2v);
    m1  = gt1 ? acc : m1;
    j1  = gt1 ? j : j1;
  }
  sPj1[sl][lane] = j1;
  sPj2[sl][lane] = j2v;
  __syncthreads();

  if (sl == 0) {
    double best = 1e300; int bk = 0x7fffffff;
    #pragma unroll
    for (int ss = 0; ss < SLC4; ++ss) {
      #pragma unroll
      for (int t = 0; t < 2; ++t) {
        int j = t ? sPj2[ss][lane] : sPj1[ss][lane];
        double asq = 0.0, dot = 0.0;
        #pragma unroll
        for (int d = 0; d < DD; ++d) {
          double a = xformD((double)anchor_raw[j * DD + d], sMnD[d], sSclD[d]);
          asq = fma(a, a, asq);
          dot = fma(x4d[d], a, dot);
        }
        double d2 = asq - 2.0 * dot;
        if (d2 < best || (d2 == best && j < bk)) { best = d2; bk = j; }
      }
    }
    sKidx[lane] = bk;
  }
  __syncthreads();

  const int k = sKidx[lane];

  float akf[DD], dxf[DD];
  float r2f = 0.f, dxak = 0.f;
  #pragma unroll
  for (int d = 0; d < DD; ++d) {
    float a = sA[k][d];
    akf[d] = a;
    float dx = (float)sOmcD[d] * (x4f[d] - a);
    dxf[d] = dx;
    r2f  = fmaf(dx, dx, r2f);
    dxak = fmaf(dx, a, dxak);
  }
  const float epsr = 1e-12f * sqrtf(r2f);
  const float asqhk = sAsqH[k];

  float q1 = 0.f, h1 = 1.f, q2 = 0.f, h2 = 1.f;
  int i1 = -1, i2 = -1;
  #pragma unroll 2
  for (int j = jlo; j < jhi; ++j) {
    float q = -dxak;
    float h = asqhk + sAsqH[j];
    const float4* ar = (const float4*)&sA[j][0];
    #pragma unroll
    for (int dq = 0; dq < 4; ++dq) {
      float4 a4 = ar[dq];
      q = fmaf(dxf[4 * dq + 0], a4.x, q);
      q = fmaf(dxf[4 * dq + 1], a4.y, q);
      q = fmaf(dxf[4 * dq + 2], a4.z, q);
      q = fmaf(dxf[4 * dq + 3], a4.w, q);
      h = fmaf(-akf[4 * dq + 0], a4.x, h);
      h = fmaf(-akf[4 * dq + 1], a4.y, h);
      h = fmaf(-akf[4 * dq + 2], a4.z, h);
      h = fmaf(-akf[4 * dq + 3], a4.w, h);
    }
    bool valid = (j != k) & (q > epsr);
    bool b1 = valid && (q * h1 > q1 * h);
    bool b2 = valid && (q * h2 > q2 * h);
    float nq2 = b1 ? q1 : (b2 ? q : q2);
    float nh2 = b1 ? h1 : (b2 ? h : h2);
    int   ni2 = b1 ? i1 : (b2 ? j : i2);
    q1 = b1 ? q : q1; h1 = b1 ? h : h1; i1 = b1 ? j : i1;
    q2 = nq2; h2 = nh2; i2 = ni2;
  }
  sRI1[sl][lane] = i1;
  sRI2[sl][lane] = i2;
  __syncthreads();

  if (sl == 0) {
    double akD[DD], dxD[DD];
    double r2 = 0.0;
    #pragma unroll
    for (int d = 0; d < DD; ++d) {
      double a = xformD((double)anchor_raw[k * DD + d], sMnD[d], sSclD[d]);
      akD[d] = a;
      double dx = sOmcD[d] * (x4d[d] - a);
      dxD[d] = dx;
      r2 = fma(dx, dx, r2);
    }
    double rD = sqrt(r2);
    double rr = fmax(rD, 1e-12);
    double ratio = rD / 1e9;

    #pragma unroll
    for (int ss = 0; ss < SLC4; ++ss) {
      #pragma unroll
      for (int t = 0; t < 2; ++t) {
        int j = t ? sRI2[ss][lane] : sRI1[ss][lane];
        if (j < 0 || j == k) continue;
        double q = 0.0, h = 0.0;
        #pragma unroll
        for (int d = 0; d < DD; ++d) {
          double aj = xformD((double)anchor_raw[j * DD + d], sMnD[d], sSclD[d]);
          double g = aj - akD[d];
          q = fma(dxD[d], g, q);
          h = fma(g, g, h);
        }
        double proj = q / rr;
        if (proj > 1e-12) {
          double cand = rD * proj / (0.5 * h);
          ratio = fmax(ratio, cand);
        }
      }
    }
    #pragma unroll
    for (int d = 0; d < DD; ++d) {
      double u = dxD[d] / rr;
      if (u > 1e-12)        ratio = fmax(ratio, rD * u / (sMxD[d] - akD[d]));
      else if (u < -1e-12)  ratio = fmax(ratio, rD * u / (sMnD[d] - akD[d]));
    }

    double sS = 1.0 / (1.0 - ratio);
    float* xo = out + (size_t)row * DD;
    #pragma unroll
    for (int d = 0; d < DD; ++d) {
      double x7 = dxD[d] * sS;
      double x8 = (x7 + sB2D[d]) * sE2D[d];
      xo[d] = (float)x8;
    }
    double lp = (double)logp_in[row] + sBaseD + lsigD
              + 17.0 * log1p(-ratio)
              - (double)mlogits[k];
    out[(size_t)Brows * DD + row] = (float)lp;
    out[coreEnd + (size_t)row * KK + k] = 1.0f;
  }
}

extern "C" void kernel_launch(void* const* d_in, const int* in_sizes, int n_in,
                              void* d_out, int out_size, void* d_ws, size_t ws_size,
                              hipStream_t stream) {
  (void)n_in; (void)out_size;
  const float* x_in   = (const float*)d_in[0];
  const float* logp   = (const float*)d_in[1];
  const float* an1w   = (const float*)d_in[2];
  const float* an1b   = (const float*)d_in[3];
  const float* an2w   = (const float*)d_in[4];
  const float* an2b   = (const float*)d_in[5];
  const float* shiftc = (const float*)d_in[6];
  const float* anchor = (const float*)d_in[7];
  const float* bmin   = (const float*)d_in[8];
  const float* bmax   = (const float*)d_in[9];
  const float* mlog   = (const float*)d_in[10];
  const int B = in_sizes[0] / DD;

  if (ws_size >= (size_t)WS_NEED_BYTES && d_ws != nullptr && (B % RPB2) == 0) {
    double* ws = (double*)d_ws;
    hipLaunchKernelGGL(vor_pre, dim3(16), dim3(256), 0, stream,
                       an1w, an2w, an2b, shiftc, anchor, bmin, bmax, mlog, ws);
    hipLaunchKernelGGL(vor7, dim3(B / RPB2), dim3(NT2), 0, stream,
                       x_in, logp, an1b, mlog,
                       (const double*)ws, (float*)d_out, B);
  } else {
    hipLaunchKernelGGL(vor_green, dim3(B / RPB), dim3(NT), 0, stream,
                       x_in, logp, an1w, an1b, an2w, an2b, shiftc, anchor,
                       bmin, bmax, mlog, (float*)d_out, B);
  }
}

// Round 18
// 97.855 us; speedup vs baseline: 1.0666x; 1.0666x over previous
//
#include <hip/hip_runtime.h>
#include <math.h>

#define DD 16
#define KK 1024

typedef float f2 __attribute__((ext_vector_type(2)));

// ---- workspace layout (doubles) ----
#define WS_A    0
#define WS_ASQ  16384
#define WS_OMC  17408
#define WS_B2   17424
#define WS_E2   17440
#define WS_MN   17456
#define WS_MX   17472
#define WS_SCL  17488
#define WS_DIM  17504
#define WS_E1   17520
#define WS_BASE 17536
#define WS_TOTD 17537
#define WS_NEED_BYTES (WS_TOTD * 8)

__device__ __forceinline__ double xformD(double rv, double mn, double scl) {
  double t = rv / (1.0 + fabs(rv));
  return (t + 1.0) * 0.5 * scl + mn;
}
__device__ __forceinline__ float xformF(float v, float mn, float mx) {
  return (v / (1.f + fabsf(v)) + 1.f) * 0.5f * (mx - mn) + mn;
}

// =============== kernel A: precompute f64 tables into ws (proven) ===============
__global__ __launch_bounds__(256) void vor_pre(
    const float* __restrict__ an1_w, const float* __restrict__ an2_w,
    const float* __restrict__ an2_b, const float* __restrict__ shift_c,
    const float* __restrict__ anchor_raw,
    const float* __restrict__ box_min, const float* __restrict__ box_max,
    const float* __restrict__ mlogits, double* __restrict__ ws)
{
  __shared__ double redD[16];
  const int tid = threadIdx.x;
  const int blk = blockIdx.x;

  if (blk == 0 && tid < DD) {
    double w1 = (double)an1_w[tid], w2 = (double)an2_w[tid];
    double sgc = 1.0 / (1.0 + exp(-(double)shift_c[tid]));
    double c = sgc * 0.98 + 0.01;
    double mn = (double)box_min[tid], mx = (double)box_max[tid];
    ws[WS_OMC + tid] = 1.0 - c;
    ws[WS_B2  + tid] = (double)an2_b[tid];
    ws[WS_E2  + tid] = exp(w2);
    ws[WS_MN  + tid] = mn;
    ws[WS_MX  + tid] = mx;
    ws[WS_SCL + tid] = mx - mn;
    ws[WS_E1  + tid] = exp(w1);
    ws[WS_DIM + tid] = -w1 - log(mx - mn) - log1p(-c) - w2;
  }
  const int j0 = blk * 64;
  for (int e = tid; e < 64 * DD; e += 256) {
    int j = j0 + (e >> 4), d = e & 15;
    double mn = (double)box_min[d];
    double scl = (double)box_max[d] - mn;
    ws[WS_A + (size_t)j * DD + d] = xformD((double)anchor_raw[j * DD + d], mn, scl);
  }
  __syncthreads();
  for (int j = j0 + tid; j < j0 + 64; j += 256) {
    double s = 0.0;
    #pragma unroll
    for (int d = 0; d < DD; ++d) { double a = ws[WS_A + (size_t)j * DD + d]; s = fma(a, a, s); }
    ws[WS_ASQ + j] = s;
  }
  if (blk != 0) return;
  float lm = -3.4e38f;
  for (int i = tid; i < KK; i += 256) lm = fmaxf(lm, mlogits[i]);
  #pragma unroll
  for (int o = 32; o > 0; o >>= 1) lm = fmaxf(lm, __shfl_xor(lm, o));
  if ((tid & 63) == 0) redD[tid >> 6] = (double)lm;
  __syncthreads();
  float gmax = (float)fmax(fmax(redD[0], redD[1]), fmax(redD[2], redD[3]));
  double lsum = 0.0;
  for (int i = tid; i < KK; i += 256) lsum += exp((double)mlogits[i] - (double)gmax);
  #pragma unroll
  for (int o = 32; o > 0; o >>= 1) lsum += __shfl_xor(lsum, o);
  if ((tid & 63) == 0) redD[4 + (tid >> 6)] = lsum;
  __syncthreads();
  if (tid == 0) {
    double lse = (double)gmax + log(redD[4] + redD[5] + redD[6] + redD[7]);
    double b = (double)DD * (log(0.98) + log(1.0 + 2.0 * (0.01 / 0.98)));
    #pragma unroll
    for (int d = 0; d < DD; ++d) b += ws[WS_DIM + d];
    ws[WS_BASE] = b + lse;
  }
}

// =============== kernel B: paired sweep-1 (16x64), vor6 sweep-2 (8x128) ===============
#define NT2 1024
#define RPB2 128
#define SL2 8            // sweep-2 slices (128 j)
#define JSL2 (KK / SL2)
#define NS1 16           // sweep-1 slices (64 j)
#define JS1 (KK / NS1)

__global__ __launch_bounds__(NT2, 4) void vor8(
    const float* __restrict__ x_in, const float* __restrict__ logp_in,
    const float* __restrict__ an1_b,
    const float* __restrict__ mlogits, const double* __restrict__ ws,
    float* __restrict__ out, int Brows)
{
  __shared__ __align__(16) float sAp[KK][DD];  // 64 KB anchors, pair-permuted {0,8,1,9,...}
  __shared__ float  sAsqH[KK];                 // 4 KB
  __shared__ double sX4D[DD][RPB2];            // 16 KB f64 x4
  __shared__ float  sLT[DD][RPB2];             // 8 KB lsig terms
  __shared__ double sD2[NS1][RPB2];            // 16 KB refined d2 per (slice16,row)
  __shared__ int    sJJ[NS1][RPB2];            // 8 KB refined j
  __shared__ float  sRat[16][64];              // 4 KB ratio cand per (wave,lane)
  __shared__ float  sOmcF[DD], sB2F[DD], sE2F[DD], sMnF[DD], sMxF[DD];

  const int tid  = threadIdx.x;
  const int w    = tid >> 6;        // 0..15
  const int lane = tid & 63;
  const int rg   = w >> 3;          // sweep-2 row-group
  const int sl   = w & 7;           // sweep-2 slice
  const int rrow = rg * 64 + lane;  // this wave's own row (sweep 2 / epilogue)
  const int r0   = lane, r1 = lane + 64;   // sweep-1 paired rows
  const int row  = blockIdx.x * RPB2 + rrow;
  const size_t coreEnd = (size_t)Brows * (DD + 1);

  if (tid < DD) {
    sOmcF[tid] = (float)ws[WS_OMC + tid];
    sB2F[tid]  = (float)ws[WS_B2 + tid];
    sE2F[tid]  = (float)ws[WS_E2 + tid];
    sMnF[tid]  = (float)ws[WS_MN + tid];
    sMxF[tid]  = (float)ws[WS_MX + tid];
  }
  // stage anchors pair-permuted from f64 ws (proven provenance)
  for (int e = tid; e < KK * DD; e += NT2) {
    int j = e >> 4, d = e & 15;
    float v = (float)ws[WS_A + (size_t)j * DD + d];
    int pos = (d < 8) ? (2 * d) : (2 * (d - 8) + 1);
    sAp[j][pos] = v;
  }
  // f64 x4 chain distributed (2 elems/thread)
  {
    const double A = 0.01, EPSB = 0.01 / 0.98;
    const double SPAN = 1.0 + 2.0 * EPSB;
    const float* xb = x_in + (size_t)blockIdx.x * RPB2 * DD;
    for (int e = tid; e < RPB2 * DD; e += NT2) {
      int rr = e >> 4, d = e & 15;
      double y1 = ((double)xb[e] + (double)an1_b[d]) * ws[WS_E1 + d];
      double sg = 1.0 / (1.0 + exp(-y1));
      double x2 = (sg - A) / (1.0 - 2.0 * A);
      double x3 = (x2 + EPSB) / SPAN;
      double x4 = x3 * ws[WS_SCL + d] + ws[WS_MN + d];
      sX4D[d][rr] = x4;
      double ay = fabs(y1);
      sLT[d][rr] = (float)(ay + 2.0 * log1p(exp(-ay)));
    }
  }
  // zero this block's f32 mask stripe
  {
    float4* mz = (float4*)(out + coreEnd + (size_t)blockIdx.x * RPB2 * KK);
    #pragma unroll 4
    for (int i = tid; i < RPB2 * KK / 4; i += NT2)
      mz[i] = make_float4(0.f, 0.f, 0.f, 0.f);
  }
  __syncthreads();     // sAp, sX4D, sLT ready

  // asqH: natural-order f32 fmaf chain from permuted storage (proven provenance)
  for (int j = tid; j < KK; j += NT2) {
    float a[DD];
    #pragma unroll
    for (int i = 0; i < 8; ++i) { a[i] = sAp[j][2 * i]; a[i + 8] = sAp[j][2 * i + 1]; }
    float acc = 0.f;
    #pragma unroll
    for (int d = 0; d < DD; ++d) acc = fmaf(a[d], a[d], acc);
    sAsqH[j] = 0.5f * acc;
  }

  // paired x4 for sweep 1
  f2 xp0[8], xp1[8];
  #pragma unroll
  for (int i = 0; i < 8; ++i) {
    xp0[i] = (f2){(float)sX4D[i][r0], (float)sX4D[i + 8][r0]};
    xp1[i] = (f2){(float)sX4D[i][r1], (float)sX4D[i + 8][r1]};
  }
  __syncthreads();     // sAsqH ready

  // ---- sweep 1 (paired pk, 16 slices of 64): top-2 per row ----
  {
    const int jlo = w * JS1, jhi = jlo + JS1;
    float m1_0 = -3.4e38f, m2_0 = -3.4e38f; int j1_0 = jlo, j2_0 = jlo;
    float m1_1 = -3.4e38f, m2_1 = -3.4e38f; int j1_1 = jlo, j2_1 = jlo;
    #pragma unroll 2
    for (int j = jlo; j < jhi; ++j) {
      const float4* ar = (const float4*)&sAp[j][0];
      float4 A0 = ar[0], A1 = ar[1], A2 = ar[2], A3 = ar[3];
      f2 p0 = (f2){A0.x, A0.y}, p1 = (f2){A0.z, A0.w};
      f2 p2 = (f2){A1.x, A1.y}, p3 = (f2){A1.z, A1.w};
      f2 p4 = (f2){A2.x, A2.y}, p5 = (f2){A2.z, A2.w};
      f2 p6 = (f2){A3.x, A3.y}, p7 = (f2){A3.z, A3.w};
      float nq = -sAsqH[j];
      f2 a0 = (f2){nq, 0.f}, a1 = (f2){nq, 0.f};
      a0 = __builtin_elementwise_fma(xp0[0], p0, a0); a1 = __builtin_elementwise_fma(xp1[0], p0, a1);
      a0 = __builtin_elementwise_fma(xp0[1], p1, a0); a1 = __builtin_elementwise_fma(xp1[1], p1, a1);
      a0 = __builtin_elementwise_fma(xp0[2], p2, a0); a1 = __builtin_elementwise_fma(xp1[2], p2, a1);
      a0 = __builtin_elementwise_fma(xp0[3], p3, a0); a1 = __builtin_elementwise_fma(xp1[3], p3, a1);
      a0 = __builtin_elementwise_fma(xp0[4], p4, a0); a1 = __builtin_elementwise_fma(xp1[4], p4, a1);
      a0 = __builtin_elementwise_fma(xp0[5], p5, a0); a1 = __builtin_elementwise_fma(xp1[5], p5, a1);
      a0 = __builtin_elementwise_fma(xp0[6], p6, a0); a1 = __builtin_elementwise_fma(xp1[6], p6, a1);
      a0 = __builtin_elementwise_fma(xp0[7], p7, a0); a1 = __builtin_elementwise_fma(xp1[7], p7, a1);
      float s0 = a0.x + a0.y, s1 = a1.x + a1.y;
      bool g1 = s0 > m1_0, g2 = s0 > m2_0;
      m2_0 = g1 ? m1_0 : (g2 ? s0 : m2_0);
      j2_0 = g1 ? j1_0 : (g2 ? j : j2_0);
      m1_0 = g1 ? s0 : m1_0;
      j1_0 = g1 ? j : j1_0;
      bool h1b = s1 > m1_1, h2b = s1 > m2_1;
      m2_1 = h1b ? m1_1 : (h2b ? s1 : m2_1);
      j2_1 = h1b ? j1_1 : (h2b ? j : j2_1);
      m1_1 = h1b ? s1 : m1_1;
      j1_1 = h1b ? j : j1_1;
    }
    // f64 refine both rows' top-2
    {
      double bD = 1e300; int bk = 0x7fffffff;
      #pragma unroll
      for (int t = 0; t < 2; ++t) {
        int j = t ? j2_0 : j1_0;
        const double* aj = ws + WS_A + (size_t)j * DD;
        double dot = 0.0;
        #pragma unroll
        for (int d = 0; d < DD; ++d) dot = fma(sX4D[d][r0], aj[d], dot);
        double d2 = ws[WS_ASQ + j] - 2.0 * dot;
        if (d2 < bD || (d2 == bD && j < bk)) { bD = d2; bk = j; }
      }
      sD2[w][r0] = bD; sJJ[w][r0] = bk;
    }
    {
      double bD = 1e300; int bk = 0x7fffffff;
      #pragma unroll
      for (int t = 0; t < 2; ++t) {
        int j = t ? j2_1 : j1_1;
        const double* aj = ws + WS_A + (size_t)j * DD;
        double dot = 0.0;
        #pragma unroll
        for (int d = 0; d < DD; ++d) dot = fma(sX4D[d][r1], aj[d], dot);
        double d2 = ws[WS_ASQ + j] - 2.0 * dot;
        if (d2 < bD || (d2 == bD && j < bk)) { bD = d2; bk = j; }
      }
      sD2[w][r1] = bD; sJJ[w][r1] = bk;
    }
  }
  __syncthreads();

  // combine k for OWN row across 16 slices (deterministic)
  int k = 0x7fffffff;
  {
    double kb = 1e300;
    #pragma unroll
    for (int ss = 0; ss < NS1; ++ss) {
      double d = sD2[ss][rrow];
      int    j = sJJ[ss][rrow];
      if (d < kb || (d == kb && j < k)) { kb = d; k = j; }
    }
  }

  // ---- sweep 2 setup (own row, vor6-identical) ----
  float x4f[DD];
  #pragma unroll
  for (int d = 0; d < DD; ++d) x4f[d] = (float)sX4D[d][rrow];
  float akf[DD];
  {
    const float4* akp = (const float4*)&sAp[k][0];
    float4 K0 = akp[0], K1 = akp[1], K2 = akp[2], K3 = akp[3];
    akf[0] = K0.x; akf[8]  = K0.y; akf[1] = K0.z; akf[9]  = K0.w;
    akf[2] = K1.x; akf[10] = K1.y; akf[3] = K1.z; akf[11] = K1.w;
    akf[4] = K2.x; akf[12] = K2.y; akf[5] = K2.z; akf[13] = K2.w;
    akf[6] = K3.x; akf[14] = K3.y; akf[7] = K3.z; akf[15] = K3.w;
  }
  float dxf[DD];
  float r2f = 0.f, dxak = 0.f;
  #pragma unroll
  for (int d = 0; d < DD; ++d) {
    float dx = sOmcF[d] * (x4f[d] - akf[d]);
    dxf[d] = dx;
    r2f  = fmaf(dx, dx, r2f);
    dxak = fmaf(dx, akf[d], dxak);
  }
  const float rf   = sqrtf(r2f);
  const float rrf  = fmaxf(rf, 1e-12f);
  const float scal = rf / rrf;
  const float epsr = 1e-12f * rf;
  const float asqhk = sAsqH[k];

  f2 dx2[8], nak2[8];
  #pragma unroll
  for (int i = 0; i < 8; ++i) {
    dx2[i]  = (f2){dxf[i], dxf[i + 8]};
    nak2[i] = (f2){-akf[i], -akf[i + 8]};
  }

  // ---- sweep 2 (pk f32, 8 slices of 128, vor6-identical) ----
  float q1 = 0.f, h1 = 1.f;
  const int jlo2 = sl * JSL2, jhi2 = jlo2 + JSL2;
  #pragma unroll 2
  for (int j = jlo2; j < jhi2; ++j) {
    const float4* ar = (const float4*)&sAp[j][0];
    float4 A0 = ar[0], A1 = ar[1], A2 = ar[2], A3 = ar[3];
    f2 p0 = (f2){A0.x, A0.y}, p1 = (f2){A0.z, A0.w};
    f2 p2 = (f2){A1.x, A1.y}, p3 = (f2){A1.z, A1.w};
    f2 p4 = (f2){A2.x, A2.y}, p5 = (f2){A2.z, A2.w};
    f2 p6 = (f2){A3.x, A3.y}, p7 = (f2){A3.z, A3.w};
    f2 q2 = (f2){-dxak, 0.f};
    f2 h2 = (f2){asqhk + sAsqH[j], 0.f};
    q2 = __builtin_elementwise_fma(dx2[0], p0, q2); h2 = __builtin_elementwise_fma(nak2[0], p0, h2);
    q2 = __builtin_elementwise_fma(dx2[1], p1, q2); h2 = __builtin_elementwise_fma(nak2[1], p1, h2);
    q2 = __builtin_elementwise_fma(dx2[2], p2, q2); h2 = __builtin_elementwise_fma(nak2[2], p2, h2);
    q2 = __builtin_elementwise_fma(dx2[3], p3, q2); h2 = __builtin_elementwise_fma(nak2[3], p3, h2);
    q2 = __builtin_elementwise_fma(dx2[4], p4, q2); h2 = __builtin_elementwise_fma(nak2[4], p4, h2);
    q2 = __builtin_elementwise_fma(dx2[5], p5, q2); h2 = __builtin_elementwise_fma(nak2[5], p5, h2);
    q2 = __builtin_elementwise_fma(dx2[6], p6, q2); h2 = __builtin_elementwise_fma(nak2[6], p6, h2);
    q2 = __builtin_elementwise_fma(dx2[7], p7, q2); h2 = __builtin_elementwise_fma(nak2[7], p7, h2);
    float q = q2.x + q2.y, h = h2.x + h2.y;
    bool upd = (j != k) & (q > epsr) & (q * h1 > q1 * h);
    q1 = upd ? q : q1;
    h1 = upd ? h : h1;
  }
  sRat[w][lane] = scal * (q1 / h1);
  __syncthreads();

  // ---- epilogue waves (sl==0, one per rg): combine ratio, box faces, outputs ----
  if (sl == 0) {
    float ratio = rf * 1e-9f;
    #pragma unroll
    for (int ss = 0; ss < SL2; ++ss) ratio = fmaxf(ratio, sRat[rg * 8 + ss][lane]);
    #pragma unroll
    for (int d = 0; d < DD; ++d) {
      float uf = dxf[d] / rrf;
      if (uf > 1e-12f)        ratio = fmaxf(ratio, rf * uf / (sMxF[d] - akf[d]));
      else if (uf < -1e-12f)  ratio = fmaxf(ratio, rf * uf / (sMnF[d] - akf[d]));
    }
    float sS = 1.0f / (1.0f - ratio);
    float xo[DD];
    float lsig = 0.f;
    #pragma unroll
    for (int d = 0; d < DD; ++d) {
      xo[d] = (dxf[d] * sS + sB2F[d]) * sE2F[d];
      lsig += sLT[d][rrow];
    }
    float4* xp = (float4*)(out + (size_t)row * DD);
    xp[0] = make_float4(xo[0], xo[1], xo[2], xo[3]);
    xp[1] = make_float4(xo[4], xo[5], xo[6], xo[7]);
    xp[2] = make_float4(xo[8], xo[9], xo[10], xo[11]);
    xp[3] = make_float4(xo[12], xo[13], xo[14], xo[15]);
    double lp = (double)logp_in[row] + ws[WS_BASE] + (double)lsig
              + 17.0 * log1p(-(double)ratio)
              - (double)mlogits[k];
    out[(size_t)Brows * DD + row] = (float)lp;
    out[coreEnd + (size_t)row * KK + k] = 1.0f;
  }
}

// =============== fallback: round-6 green kernel (unchanged) ===============
#define NT 256
#define RPB 64
#define SLC4 4
#define JSL4 (KK / SLC4)

__global__ __launch_bounds__(NT, 2) void vor_green(
    const float* __restrict__ x_in, const float* __restrict__ logp_in,
    const float* __restrict__ an1_w, const float* __restrict__ an1_b,
    const float* __restrict__ an2_w, const float* __restrict__ an2_b,
    const float* __restrict__ shift_c, const float* __restrict__ anchor_raw,
    const float* __restrict__ box_min, const float* __restrict__ box_max,
    const float* __restrict__ mlogits,
    float* __restrict__ out, int Brows)
{
  __shared__ __align__(16) float sA[KK][DD];
  __shared__ float  sAsqH[KK];
  __shared__ float  sX4T[DD][RPB];
  __shared__ int    sPj1[SLC4][RPB], sPj2[SLC4][RPB];
  __shared__ int    sRI1[SLC4][RPB], sRI2[SLC4][RPB];
  __shared__ double sPartD[8];
  __shared__ double sE1D[DD], sB1D[DD], sOmcD[DD], sB2D[DD], sE2D[DD];
  __shared__ double sMnD[DD], sMxD[DD], sSclD[DD], sDimD[DD];
  __shared__ double sBaseD;
  __shared__ int    sKidx[RPB];

  const int tid  = threadIdx.x;
  const int sl   = tid >> 6;
  const int lane = tid & 63;
  const int row  = blockIdx.x * RPB + lane;
  const size_t coreEnd = (size_t)Brows * (DD + 1);

  for (int e = tid; e < KK * DD / 4; e += NT) {
    float4 raw = ((const float4*)anchor_raw)[e];
    float4 bmn = ((const float4*)box_min)[e & 3];
    float4 bmx = ((const float4*)box_max)[e & 3];
    float4 o;
    o.x = xformF(raw.x, bmn.x, bmx.x);
    o.y = xformF(raw.y, bmn.y, bmx.y);
    o.z = xformF(raw.z, bmn.z, bmx.z);
    o.w = xformF(raw.w, bmn.w, bmx.w);
    ((float4*)sA)[e] = o;
  }
  if (tid < DD) {
    double w1 = (double)an1_w[tid];
    sE1D[tid] = exp(w1);
    sB1D[tid] = (double)an1_b[tid];
    double sgc = 1.0 / (1.0 + exp(-(double)shift_c[tid]));
    double c = sgc * 0.98 + 0.01;
    sOmcD[tid] = 1.0 - c;
    double mn = (double)box_min[tid], mx = (double)box_max[tid];
    sMnD[tid] = mn; sMxD[tid] = mx; sSclD[tid] = mx - mn;
    double w2 = (double)an2_w[tid];
    sE2D[tid] = exp(w2);
    sB2D[tid] = (double)an2_b[tid];
    sDimD[tid] = -w1 - log(mx - mn) - log1p(-c) - w2;
  }
  __syncthreads();

  for (int j = tid; j < KK; j += NT) {
    float acc = 0.f;
    #pragma unroll
    for (int d = 0; d < DD; ++d) { float a = sA[j][d]; acc = fmaf(a, a, acc); }
    sAsqH[j] = 0.5f * acc;
  }

  float lm = -3.4e38f;
  for (int i = tid; i < KK; i += NT) lm = fmaxf(lm, mlogits[i]);
  #pragma unroll
  for (int o = 32; o > 0; o >>= 1) lm = fmaxf(lm, __shfl_xor(lm, o));
  if (lane == 0) sPartD[sl] = (double)lm;
  __syncthreads();
  float gmax = (float)fmax(fmax(sPartD[0], sPartD[1]), fmax(sPartD[2], sPartD[3]));
  double lsum = 0.0;
  for (int i = tid; i < KK; i += NT) lsum += exp((double)mlogits[i] - (double)gmax);
  #pragma unroll
  for (int o = 32; o > 0; o >>= 1) lsum += __shfl_xor(lsum, o);
  if (lane == 0) sPartD[4 + sl] = lsum;
  __syncthreads();
  if (tid == 0) {
    double lse = (double)gmax + log(sPartD[4] + sPartD[5] + sPartD[6] + sPartD[7]);
    double b = (double)DD * (log(0.98) + log(1.0 + 2.0 * (0.01 / 0.98)));
    #pragma unroll
    for (int d = 0; d < DD; ++d) b += sDimD[d];
    sBaseD = b + lse;
  }

  double x4d[DD];
  double lsigD = 0.0;
  if (sl == 0) {
    const double A = 0.01, EPSB = 0.01 / 0.98;
    const double SPAN = 1.0 + 2.0 * EPSB;
    const float* xr = x_in + (size_t)row * DD;
    #pragma unroll
    for (int d = 0; d < DD; ++d) {
      double y1 = ((double)xr[d] + sB1D[d]) * sE1D[d];
      double sg = 1.0 / (1.0 + exp(-y1));
      double x2 = (sg - A) / (1.0 - 2.0 * A);
      double x3 = (x2 + EPSB) / SPAN;
      double x4 = x3 * sSclD[d] + sMnD[d];
      x4d[d] = x4;
      sX4T[d][lane] = (float)x4;
      double ay = fabs(y1);
      lsigD += ay + 2.0 * log1p(exp(-ay));
    }
  }
  {
    float4* mz = (float4*)(out + coreEnd + (size_t)blockIdx.x * RPB * KK);
    #pragma unroll 4
    for (int i = tid; i < RPB * KK / 4; i += NT)
      mz[i] = make_float4(0.f, 0.f, 0.f, 0.f);
  }
  __syncthreads();

  float x4f[DD];
  #pragma unroll
  for (int d = 0; d < DD; ++d) x4f[d] = sX4T[d][lane];

  float m1 = -3.4e38f, m2v = -3.4e38f;
  int j1 = 0x7fffffff, j2v = 0x7fffffff;
  const int jlo = sl * JSL4, jhi = jlo + JSL4;
  #pragma unroll 2
  for (int j = jlo; j < jhi; ++j) {
    float acc = -sAsqH[j];
    const float4* ar = (const float4*)&sA[j][0];
    #pragma unroll
    for (int dq = 0; dq < 4; ++dq) {
      float4 a4 = ar[dq];
      acc = fmaf(x4f[4 * dq + 0], a4.x, acc);
      acc = fmaf(x4f[4 * dq + 1], a4.y, acc);
      acc = fmaf(x4f[4 * dq + 2], a4.z, acc);
      acc = fmaf(x4f[4 * dq + 3], a4.w, acc);
    }
    bool gt1 = acc > m1;
    bool gt2 = acc > m2v;
    m2v = gt1 ? m1 : (gt2 ? acc : m2v);
    j2v = gt1 ? j1 : (gt2 ? j : j2v);
    m1  = gt1 ? acc : m1;
    j1  = gt1 ? j : j1;
  }
  sPj1[sl][lane] = j1;
  sPj2[sl][lane] = j2v;
  __syncthreads();

  if (sl == 0) {
    double best = 1e300; int bk = 0x7fffffff;
    #pragma unroll
    for (int ss = 0; ss < SLC4; ++ss) {
      #pragma unroll
      for (int t = 0; t < 2; ++t) {
        int j = t ? sPj2[ss][lane] : sPj1[ss][lane];
        double asq = 0.0, dot = 0.0;
        #pragma unroll
        for (int d = 0; d < DD; ++d) {
          double a = xformD((double)anchor_raw[j * DD + d], sMnD[d], sSclD[d]);
          asq = fma(a, a, asq);
          dot = fma(x4d[d], a, dot);
        }
        double d2 = asq - 2.0 * dot;
        if (d2 < best || (d2 == best && j < bk)) { best = d2; bk = j; }
      }
    }
    sKidx[lane] = bk;
  }
  __syncthreads();

  const int k = sKidx[lane];

  float akf[DD], dxf[DD];
  float r2f = 0.f, dxak = 0.f;
  #pragma unroll
  for (int d = 0; d < DD; ++d) {
    float a = sA[k][d];
    akf[d] = a;
    float dx = (float)sOmcD[d] * (x4f[d] - a);
    dxf[d] = dx;
    r2f  = fmaf(dx, dx, r2f);
    dxak = fmaf(dx, a, dxak);
  }
  const float epsr = 1e-12f * sqrtf(r2f);
  const float asqhk = sAsqH[k];

  float q1 = 0.f, h1 = 1.f, q2 = 0.f, h2 = 1.f;
  int i1 = -1, i2 = -1;
  #pragma unroll 2
  for (int j = jlo; j < jhi; ++j) {
    float q = -dxak;
    float h = asqhk + sAsqH[j];
    const float4* ar = (const float4*)&sA[j][0];
    #pragma unroll
    for (int dq = 0; dq < 4; ++dq) {
      float4 a4 = ar[dq];
      q = fmaf(dxf[4 * dq + 0], a4.x, q);
      q = fmaf(dxf[4 * dq + 1], a4.y, q);
      q = fmaf(dxf[4 * dq + 2], a4.z, q);
      q = fmaf(dxf[4 * dq + 3], a4.w, q);
      h = fmaf(-akf[4 * dq + 0], a4.x, h);
      h = fmaf(-akf[4 * dq + 1], a4.y, h);
      h = fmaf(-akf[4 * dq + 2], a4.z, h);
      h = fmaf(-akf[4 * dq + 3], a4.w, h);
    }
    bool valid = (j != k) & (q > epsr);
    bool b1 = valid && (q * h1 > q1 * h);
    bool b2 = valid && (q * h2 > q2 * h);
    float nq2 = b1 ? q1 : (b2 ? q : q2);
    float nh2 = b1 ? h1 : (b2 ? h : h2);
    int   ni2 = b1 ? i1 : (b2 ? j : i2);
    q1 = b1 ? q : q1; h1 = b1 ? h : h1; i1 = b1 ? j : i1;
    q2 = nq2; h2 = nh2; i2 = ni2;
  }
  sRI1[sl][lane] = i1;
  sRI2[sl][lane] = i2;
  __syncthreads();

  if (sl == 0) {
    double akD[DD], dxD[DD];
    double r2 = 0.0;
    #pragma unroll
    for (int d = 0; d < DD; ++d) {
      double a = xformD((double)anchor_raw[k * DD + d], sMnD[d], sSclD[d]);
      akD[d] = a;
      double dx = sOmcD[d] * (x4d[d] - a);
      dxD[d] = dx;
      r2 = fma(dx, dx, r2);
    }
    double rD = sqrt(r2);
    double rr = fmax(rD, 1e-12);
    double ratio = rD / 1e9;

    #pragma unroll
    for (int ss = 0; ss < SLC4; ++ss) {
      #pragma unroll
      for (int t = 0; t < 2; ++t) {
        int j = t ? sRI2[ss][lane] : sRI1[ss][lane];
        if (j < 0 || j == k) continue;
        double q = 0.0, h = 0.0;
        #pragma unroll
        for (int d = 0; d < DD; ++d) {
          double aj = xformD((double)anchor_raw[j * DD + d], sMnD[d], sSclD[d]);
          double g = aj - akD[d];
          q = fma(dxD[d], g, q);
          h = fma(g, g, h);
        }
        double proj = q / rr;
        if (proj > 1e-12) {
          double cand = rD * proj / (0.5 * h);
          ratio = fmax(ratio, cand);
        }
      }
    }
    #pragma unroll
    for (int d = 0; d < DD; ++d) {
      double u = dxD[d] / rr;
      if (u > 1e-12)        ratio = fmax(ratio, rD * u / (sMxD[d] - akD[d]));
      else if (u < -1e-12)  ratio = fmax(ratio, rD * u / (sMnD[d] - akD[d]));
    }

    double sS = 1.0 / (1.0 - ratio);
    float* xo = out + (size_t)row * DD;
    #pragma unroll
    for (int d = 0; d < DD; ++d) {
      double x7 = dxD[d] * sS;
      double x8 = (x7 + sB2D[d]) * sE2D[d];
      xo[d] = (float)x8;
    }
    double lp = (double)logp_in[row] + sBaseD + lsigD
              + 17.0 * log1p(-ratio)
              - (double)mlogits[k];
    out[(size_t)Brows * DD + row] = (float)lp;
    out[coreEnd + (size_t)row * KK + k] = 1.0f;
  }
}

extern "C" void kernel_launch(void* const* d_in, const int* in_sizes, int n_in,
                              void* d_out, int out_size, void* d_ws, size_t ws_size,
                              hipStream_t stream) {
  (void)n_in; (void)out_size;
  const float* x_in   = (const float*)d_in[0];
  const float* logp   = (const float*)d_in[1];
  const float* an1w   = (const float*)d_in[2];
  const float* an1b   = (const float*)d_in[3];
  const float* an2w   = (const float*)d_in[4];
  const float* an2b   = (const float*)d_in[5];
  const float* shiftc = (const float*)d_in[6];
  const float* anchor = (const float*)d_in[7];
  const float* bmin   = (const float*)d_in[8];
  const float* bmax   = (const float*)d_in[9];
  const float* mlog   = (const float*)d_in[10];
  const int B = in_sizes[0] / DD;

  if (ws_size >= (size_t)WS_NEED_BYTES && d_ws != nullptr && (B % RPB2) == 0) {
    double* ws = (double*)d_ws;
    hipLaunchKernelGGL(vor_pre, dim3(16), dim3(256), 0, stream,
                       an1w, an2w, an2b, shiftc, anchor, bmin, bmax, mlog, ws);
    hipLaunchKernelGGL(vor8, dim3(B / RPB2), dim3(NT2), 0, stream,
                       x_in, logp, an1b, mlog,
                       (const double*)ws, (float*)d_out, B);
  } else {
    hipLaunchKernelGGL(vor_green, dim3(B / RPB), dim3(NT), 0, stream,
                       x_in, logp, an1w, an1b, an2w, an2b, shiftc, anchor,
                       bmin, bmax, mlog, (float*)d_out, B);
  }
}

// Round 19
// 97.227 us; speedup vs baseline: 1.0735x; 1.0065x over previous
//
#include <hip/hip_runtime.h>
#include <math.h>

#define DD 16
#define KK 1024

typedef float f2 __attribute__((ext_vector_type(2)));

// ---- workspace layout (doubles) ----
#define WS_A    0
#define WS_ASQ  16384
#define WS_OMC  17408
#define WS_B2   17424
#define WS_E2   17440
#define WS_MN   17456
#define WS_MX   17472
#define WS_SCL  17488
#define WS_DIM  17504
#define WS_E1   17520
#define WS_BASE 17536
#define WS_TOTD 17537
#define WS_NEED_BYTES (WS_TOTD * 8)

__device__ __forceinline__ double xformD(double rv, double mn, double scl) {
  double t = rv / (1.0 + fabs(rv));
  return (t + 1.0) * 0.5 * scl + mn;
}
__device__ __forceinline__ float xformF(float v, float mn, float mx) {
  return (v / (1.f + fabsf(v)) + 1.f) * 0.5f * (mx - mn) + mn;
}

// =============== kernel A: precompute f64 tables into ws (proven) ===============
__global__ __launch_bounds__(256) void vor_pre(
    const float* __restrict__ an1_w, const float* __restrict__ an2_w,
    const float* __restrict__ an2_b, const float* __restrict__ shift_c,
    const float* __restrict__ anchor_raw,
    const float* __restrict__ box_min, const float* __restrict__ box_max,
    const float* __restrict__ mlogits, double* __restrict__ ws)
{
  __shared__ double redD[16];
  const int tid = threadIdx.x;
  const int blk = blockIdx.x;

  if (blk == 0 && tid < DD) {
    double w1 = (double)an1_w[tid], w2 = (double)an2_w[tid];
    double sgc = 1.0 / (1.0 + exp(-(double)shift_c[tid]));
    double c = sgc * 0.98 + 0.01;
    double mn = (double)box_min[tid], mx = (double)box_max[tid];
    ws[WS_OMC + tid] = 1.0 - c;
    ws[WS_B2  + tid] = (double)an2_b[tid];
    ws[WS_E2  + tid] = exp(w2);
    ws[WS_MN  + tid] = mn;
    ws[WS_MX  + tid] = mx;
    ws[WS_SCL + tid] = mx - mn;
    ws[WS_E1  + tid] = exp(w1);
    ws[WS_DIM + tid] = -w1 - log(mx - mn) - log1p(-c) - w2;
  }
  const int j0 = blk * 64;
  for (int e = tid; e < 64 * DD; e += 256) {
    int j = j0 + (e >> 4), d = e & 15;
    double mn = (double)box_min[d];
    double scl = (double)box_max[d] - mn;
    ws[WS_A + (size_t)j * DD + d] = xformD((double)anchor_raw[j * DD + d], mn, scl);
  }
  __syncthreads();
  for (int j = j0 + tid; j < j0 + 64; j += 256) {
    double s = 0.0;
    #pragma unroll
    for (int d = 0; d < DD; ++d) { double a = ws[WS_A + (size_t)j * DD + d]; s = fma(a, a, s); }
    ws[WS_ASQ + j] = s;
  }
  if (blk != 0) return;
  float lm = -3.4e38f;
  for (int i = tid; i < KK; i += 256) lm = fmaxf(lm, mlogits[i]);
  #pragma unroll
  for (int o = 32; o > 0; o >>= 1) lm = fmaxf(lm, __shfl_xor(lm, o));
  if ((tid & 63) == 0) redD[tid >> 6] = (double)lm;
  __syncthreads();
  float gmax = (float)fmax(fmax(redD[0], redD[1]), fmax(redD[2], redD[3]));
  double lsum = 0.0;
  for (int i = tid; i < KK; i += 256) lsum += exp((double)mlogits[i] - (double)gmax);
  #pragma unroll
  for (int o = 32; o > 0; o >>= 1) lsum += __shfl_xor(lsum, o);
  if ((tid & 63) == 0) redD[4 + (tid >> 6)] = lsum;
  __syncthreads();
  if (tid == 0) {
    double lse = (double)gmax + log(redD[4] + redD[5] + redD[6] + redD[7]);
    double b = (double)DD * (log(0.98) + log(1.0 + 2.0 * (0.01 / 0.98)));
    #pragma unroll
    for (int d = 0; d < DD; ++d) b += ws[WS_DIM + d];
    ws[WS_BASE] = b + lse;
  }
}

// =============== kernel B: vor8 + unroll-4 sweeps ===============
#define NT2 1024
#define RPB2 128
#define SL2 8            // sweep-2 slices (128 j)
#define JSL2 (KK / SL2)
#define NS1 16           // sweep-1 slices (64 j)
#define JS1 (KK / NS1)

__global__ __launch_bounds__(NT2, 4) void vor9(
    const float* __restrict__ x_in, const float* __restrict__ logp_in,
    const float* __restrict__ an1_b,
    const float* __restrict__ mlogits, const double* __restrict__ ws,
    float* __restrict__ out, int Brows)
{
  __shared__ __align__(16) float sAp[KK][DD];  // 64 KB anchors, pair-permuted {0,8,1,9,...}
  __shared__ float  sAsqH[KK];                 // 4 KB
  __shared__ double sX4D[DD][RPB2];            // 16 KB f64 x4
  __shared__ float  sLT[DD][RPB2];             // 8 KB lsig terms
  __shared__ double sD2[NS1][RPB2];            // 16 KB refined d2 per (slice16,row)
  __shared__ int    sJJ[NS1][RPB2];            // 8 KB refined j
  __shared__ float  sRat[16][64];              // 4 KB ratio cand per (wave,lane)
  __shared__ float  sOmcF[DD], sB2F[DD], sE2F[DD], sMnF[DD], sMxF[DD];

  const int tid  = threadIdx.x;
  const int w    = tid >> 6;        // 0..15
  const int lane = tid & 63;
  const int rg   = w >> 3;          // sweep-2 row-group
  const int sl   = w & 7;           // sweep-2 slice
  const int rrow = rg * 64 + lane;  // this wave's own row (sweep 2 / epilogue)
  const int r0   = lane, r1 = lane + 64;   // sweep-1 paired rows
  const int row  = blockIdx.x * RPB2 + rrow;
  const size_t coreEnd = (size_t)Brows * (DD + 1);

  if (tid < DD) {
    sOmcF[tid] = (float)ws[WS_OMC + tid];
    sB2F[tid]  = (float)ws[WS_B2 + tid];
    sE2F[tid]  = (float)ws[WS_E2 + tid];
    sMnF[tid]  = (float)ws[WS_MN + tid];
    sMxF[tid]  = (float)ws[WS_MX + tid];
  }
  // stage anchors pair-permuted from f64 ws (proven provenance)
  for (int e = tid; e < KK * DD; e += NT2) {
    int j = e >> 4, d = e & 15;
    float v = (float)ws[WS_A + (size_t)j * DD + d];
    int pos = (d < 8) ? (2 * d) : (2 * (d - 8) + 1);
    sAp[j][pos] = v;
  }
  // f64 x4 chain distributed (2 elems/thread)
  {
    const double A = 0.01, EPSB = 0.01 / 0.98;
    const double SPAN = 1.0 + 2.0 * EPSB;
    const float* xb = x_in + (size_t)blockIdx.x * RPB2 * DD;
    for (int e = tid; e < RPB2 * DD; e += NT2) {
      int rr = e >> 4, d = e & 15;
      double y1 = ((double)xb[e] + (double)an1_b[d]) * ws[WS_E1 + d];
      double sg = 1.0 / (1.0 + exp(-y1));
      double x2 = (sg - A) / (1.0 - 2.0 * A);
      double x3 = (x2 + EPSB) / SPAN;
      double x4 = x3 * ws[WS_SCL + d] + ws[WS_MN + d];
      sX4D[d][rr] = x4;
      double ay = fabs(y1);
      sLT[d][rr] = (float)(ay + 2.0 * log1p(exp(-ay)));
    }
  }
  // zero this block's f32 mask stripe
  {
    float4* mz = (float4*)(out + coreEnd + (size_t)blockIdx.x * RPB2 * KK);
    #pragma unroll 4
    for (int i = tid; i < RPB2 * KK / 4; i += NT2)
      mz[i] = make_float4(0.f, 0.f, 0.f, 0.f);
  }
  __syncthreads();     // sAp, sX4D, sLT ready

  // asqH: natural-order f32 fmaf chain from permuted storage (proven provenance)
  for (int j = tid; j < KK; j += NT2) {
    float a[DD];
    #pragma unroll
    for (int i = 0; i < 8; ++i) { a[i] = sAp[j][2 * i]; a[i + 8] = sAp[j][2 * i + 1]; }
    float acc = 0.f;
    #pragma unroll
    for (int d = 0; d < DD; ++d) acc = fmaf(a[d], a[d], acc);
    sAsqH[j] = 0.5f * acc;
  }

  // paired x4 for sweep 1
  f2 xp0[8], xp1[8];
  #pragma unroll
  for (int i = 0; i < 8; ++i) {
    xp0[i] = (f2){(float)sX4D[i][r0], (float)sX4D[i + 8][r0]};
    xp1[i] = (f2){(float)sX4D[i][r1], (float)sX4D[i + 8][r1]};
  }
  __syncthreads();     // sAsqH ready

  // ---- sweep 1 (paired pk, 16 slices of 64, UNROLL 4): top-2 per row ----
  {
    const int jlo = w * JS1, jhi = jlo + JS1;
    float m1_0 = -3.4e38f, m2_0 = -3.4e38f; int j1_0 = jlo, j2_0 = jlo;
    float m1_1 = -3.4e38f, m2_1 = -3.4e38f; int j1_1 = jlo, j2_1 = jlo;
    #pragma unroll 4
    for (int j = jlo; j < jhi; ++j) {
      const float4* ar = (const float4*)&sAp[j][0];
      float4 A0 = ar[0], A1 = ar[1], A2 = ar[2], A3 = ar[3];
      f2 p0 = (f2){A0.x, A0.y}, p1 = (f2){A0.z, A0.w};
      f2 p2 = (f2){A1.x, A1.y}, p3 = (f2){A1.z, A1.w};
      f2 p4 = (f2){A2.x, A2.y}, p5 = (f2){A2.z, A2.w};
      f2 p6 = (f2){A3.x, A3.y}, p7 = (f2){A3.z, A3.w};
      float nq = -sAsqH[j];
      f2 a0 = (f2){nq, 0.f}, a1 = (f2){nq, 0.f};
      a0 = __builtin_elementwise_fma(xp0[0], p0, a0); a1 = __builtin_elementwise_fma(xp1[0], p0, a1);
      a0 = __builtin_elementwise_fma(xp0[1], p1, a0); a1 = __builtin_elementwise_fma(xp1[1], p1, a1);
      a0 = __builtin_elementwise_fma(xp0[2], p2, a0); a1 = __builtin_elementwise_fma(xp1[2], p2, a1);
      a0 = __builtin_elementwise_fma(xp0[3], p3, a0); a1 = __builtin_elementwise_fma(xp1[3], p3, a1);
      a0 = __builtin_elementwise_fma(xp0[4], p4, a0); a1 = __builtin_elementwise_fma(xp1[4], p4, a1);
      a0 = __builtin_elementwise_fma(xp0[5], p5, a0); a1 = __builtin_elementwise_fma(xp1[5], p5, a1);
      a0 = __builtin_elementwise_fma(xp0[6], p6, a0); a1 = __builtin_elementwise_fma(xp1[6], p6, a1);
      a0 = __builtin_elementwise_fma(xp0[7], p7, a0); a1 = __builtin_elementwise_fma(xp1[7], p7, a1);
      float s0 = a0.x + a0.y, s1 = a1.x + a1.y;
      bool g1 = s0 > m1_0, g2 = s0 > m2_0;
      m2_0 = g1 ? m1_0 : (g2 ? s0 : m2_0);
      j2_0 = g1 ? j1_0 : (g2 ? j : j2_0);
      m1_0 = g1 ? s0 : m1_0;
      j1_0 = g1 ? j : j1_0;
      bool h1b = s1 > m1_1, h2b = s1 > m2_1;
      m2_1 = h1b ? m1_1 : (h2b ? s1 : m2_1);
      j2_1 = h1b ? j1_1 : (h2b ? j : j2_1);
      m1_1 = h1b ? s1 : m1_1;
      j1_1 = h1b ? j : j1_1;
    }
    // f64 refine both rows' top-2
    {
      double bD = 1e300; int bk = 0x7fffffff;
      #pragma unroll
      for (int t = 0; t < 2; ++t) {
        int j = t ? j2_0 : j1_0;
        const double* aj = ws + WS_A + (size_t)j * DD;
        double dot = 0.0;
        #pragma unroll
        for (int d = 0; d < DD; ++d) dot = fma(sX4D[d][r0], aj[d], dot);
        double d2 = ws[WS_ASQ + j] - 2.0 * dot;
        if (d2 < bD || (d2 == bD && j < bk)) { bD = d2; bk = j; }
      }
      sD2[w][r0] = bD; sJJ[w][r0] = bk;
    }
    {
      double bD = 1e300; int bk = 0x7fffffff;
      #pragma unroll
      for (int t = 0; t < 2; ++t) {
        int j = t ? j2_1 : j1_1;
        const double* aj = ws + WS_A + (size_t)j * DD;
        double dot = 0.0;
        #pragma unroll
        for (int d = 0; d < DD; ++d) dot = fma(sX4D[d][r1], aj[d], dot);
        double d2 = ws[WS_ASQ + j] - 2.0 * dot;
        if (d2 < bD || (d2 == bD && j < bk)) { bD = d2; bk = j; }
      }
      sD2[w][r1] = bD; sJJ[w][r1] = bk;
    }
  }
  __syncthreads();

  // combine k for OWN row across 16 slices (deterministic)
  int k = 0x7fffffff;
  {
    double kb = 1e300;
    #pragma unroll
    for (int ss = 0; ss < NS1; ++ss) {
      double d = sD2[ss][rrow];
      int    j = sJJ[ss][rrow];
      if (d < kb || (d == kb && j < k)) { kb = d; k = j; }
    }
  }

  // ---- sweep 2 setup (own row) ----
  float x4f[DD];
  #pragma unroll
  for (int d = 0; d < DD; ++d) x4f[d] = (float)sX4D[d][rrow];
  float akf[DD];
  {
    const float4* akp = (const float4*)&sAp[k][0];
    float4 K0 = akp[0], K1 = akp[1], K2 = akp[2], K3 = akp[3];
    akf[0] = K0.x; akf[8]  = K0.y; akf[1] = K0.z; akf[9]  = K0.w;
    akf[2] = K1.x; akf[10] = K1.y; akf[3] = K1.z; akf[11] = K1.w;
    akf[4] = K2.x; akf[12] = K2.y; akf[5] = K2.z; akf[13] = K2.w;
    akf[6] = K3.x; akf[14] = K3.y; akf[7] = K3.z; akf[15] = K3.w;
  }
  float dxf[DD];
  float r2f = 0.f, dxak = 0.f;
  #pragma unroll
  for (int d = 0; d < DD; ++d) {
    float dx = sOmcF[d] * (x4f[d] - akf[d]);
    dxf[d] = dx;
    r2f  = fmaf(dx, dx, r2f);
    dxak = fmaf(dx, akf[d], dxak);
  }
  const float rf   = sqrtf(r2f);
  const float rrf  = fmaxf(rf, 1e-12f);
  const float scal = rf / rrf;
  const float epsr = 1e-12f * rf;
  const float asqhk = sAsqH[k];

  f2 dx2[8], nak2[8];
  #pragma unroll
  for (int i = 0; i < 8; ++i) {
    dx2[i]  = (f2){dxf[i], dxf[i + 8]};
    nak2[i] = (f2){-akf[i], -akf[i + 8]};
  }

  // ---- sweep 2 (pk f32, 8 slices of 128, UNROLL 4) ----
  float q1 = 0.f, h1 = 1.f;
  const int jlo2 = sl * JSL2, jhi2 = jlo2 + JSL2;
  #pragma unroll 4
  for (int j = jlo2; j < jhi2; ++j) {
    const float4* ar = (const float4*)&sAp[j][0];
    float4 A0 = ar[0], A1 = ar[1], A2 = ar[2], A3 = ar[3];
    f2 p0 = (f2){A0.x, A0.y}, p1 = (f2){A0.z, A0.w};
    f2 p2 = (f2){A1.x, A1.y}, p3 = (f2){A1.z, A1.w};
    f2 p4 = (f2){A2.x, A2.y}, p5 = (f2){A2.z, A2.w};
    f2 p6 = (f2){A3.x, A3.y}, p7 = (f2){A3.z, A3.w};
    f2 q2 = (f2){-dxak, 0.f};
    f2 h2 = (f2){asqhk + sAsqH[j], 0.f};
    q2 = __builtin_elementwise_fma(dx2[0], p0, q2); h2 = __builtin_elementwise_fma(nak2[0], p0, h2);
    q2 = __builtin_elementwise_fma(dx2[1], p1, q2); h2 = __builtin_elementwise_fma(nak2[1], p1, h2);
    q2 = __builtin_elementwise_fma(dx2[2], p2, q2); h2 = __builtin_elementwise_fma(nak2[2], p2, h2);
    q2 = __builtin_elementwise_fma(dx2[3], p3, q2); h2 = __builtin_elementwise_fma(nak2[3], p3, h2);
    q2 = __builtin_elementwise_fma(dx2[4], p4, q2); h2 = __builtin_elementwise_fma(nak2[4], p4, h2);
    q2 = __builtin_elementwise_fma(dx2[5], p5, q2); h2 = __builtin_elementwise_fma(nak2[5], p5, h2);
    q2 = __builtin_elementwise_fma(dx2[6], p6, q2); h2 = __builtin_elementwise_fma(nak2[6], p6, h2);
    q2 = __builtin_elementwise_fma(dx2[7], p7, q2); h2 = __builtin_elementwise_fma(nak2[7], p7, h2);
    float q = q2.x + q2.y, h = h2.x + h2.y;
    bool upd = (j != k) & (q > epsr) & (q * h1 > q1 * h);
    q1 = upd ? q : q1;
    h1 = upd ? h : h1;
  }
  sRat[w][lane] = scal * (q1 / h1);
  __syncthreads();

  // ---- epilogue waves (sl==0, one per rg): combine ratio, box faces, outputs ----
  if (sl == 0) {
    float ratio = rf * 1e-9f;
    #pragma unroll
    for (int ss = 0; ss < SL2; ++ss) ratio = fmaxf(ratio, sRat[rg * 8 + ss][lane]);
    #pragma unroll
    for (int d = 0; d < DD; ++d) {
      float uf = dxf[d] / rrf;
      if (uf > 1e-12f)        ratio = fmaxf(ratio, rf * uf / (sMxF[d] - akf[d]));
      else if (uf < -1e-12f)  ratio = fmaxf(ratio, rf * uf / (sMnF[d] - akf[d]));
    }
    float sS = 1.0f / (1.0f - ratio);
    float xo[DD];
    float lsig = 0.f;
    #pragma unroll
    for (int d = 0; d < DD; ++d) {
      xo[d] = (dxf[d] * sS + sB2F[d]) * sE2F[d];
      lsig += sLT[d][rrow];
    }
    float4* xp = (float4*)(out + (size_t)row * DD);
    xp[0] = make_float4(xo[0], xo[1], xo[2], xo[3]);
    xp[1] = make_float4(xo[4], xo[5], xo[6], xo[7]);
    xp[2] = make_float4(xo[8], xo[9], xo[10], xo[11]);
    xp[3] = make_float4(xo[12], xo[13], xo[14], xo[15]);
    double lp = (double)logp_in[row] + ws[WS_BASE] + (double)lsig
              + 17.0 * log1p(-(double)ratio)
              - (double)mlogits[k];
    out[(size_t)Brows * DD + row] = (float)lp;
    out[coreEnd + (size_t)row * KK + k] = 1.0f;
  }
}

// =============== fallback: round-6 green kernel (unchanged) ===============
#define NT 256
#define RPB 64
#define SLC4 4
#define JSL4 (KK / SLC4)

__global__ __launch_bounds__(NT, 2) void vor_green(
    const float* __restrict__ x_in, const float* __restrict__ logp_in,
    const float* __restrict__ an1_w, const float* __restrict__ an1_b,
    const float* __restrict__ an2_w, const float* __restrict__ an2_b,
    const float* __restrict__ shift_c, const float* __restrict__ anchor_raw,
    const float* __restrict__ box_min, const float* __restrict__ box_max,
    const float* __restrict__ mlogits,
    float* __restrict__ out, int Brows)
{
  __shared__ __align__(16) float sA[KK][DD];
  __shared__ float  sAsqH[KK];
  __shared__ float  sX4T[DD][RPB];
  __shared__ int    sPj1[SLC4][RPB], sPj2[SLC4][RPB];
  __shared__ int    sRI1[SLC4][RPB], sRI2[SLC4][RPB];
  __shared__ double sPartD[8];
  __shared__ double sE1D[DD], sB1D[DD], sOmcD[DD], sB2D[DD], sE2D[DD];
  __shared__ double sMnD[DD], sMxD[DD], sSclD[DD], sDimD[DD];
  __shared__ double sBaseD;
  __shared__ int    sKidx[RPB];

  const int tid  = threadIdx.x;
  const int sl   = tid >> 6;
  const int lane = tid & 63;
  const int row  = blockIdx.x * RPB + lane;
  const size_t coreEnd = (size_t)Brows * (DD + 1);

  for (int e = tid; e < KK * DD / 4; e += NT) {
    float4 raw = ((const float4*)anchor_raw)[e];
    float4 bmn = ((const float4*)box_min)[e & 3];
    float4 bmx = ((const float4*)box_max)[e & 3];
    float4 o;
    o.x = xformF(raw.x, bmn.x, bmx.x);
    o.y = xformF(raw.y, bmn.y, bmx.y);
    o.z = xformF(raw.z, bmn.z, bmx.z);
    o.w = xformF(raw.w, bmn.w, bmx.w);
    ((float4*)sA)[e] = o;
  }
  if (tid < DD) {
    double w1 = (double)an1_w[tid];
    sE1D[tid] = exp(w1);
    sB1D[tid] = (double)an1_b[tid];
    double sgc = 1.0 / (1.0 + exp(-(double)shift_c[tid]));
    double c = sgc * 0.98 + 0.01;
    sOmcD[tid] = 1.0 - c;
    double mn = (double)box_min[tid], mx = (double)box_max[tid];
    sMnD[tid] = mn; sMxD[tid] = mx; sSclD[tid] = mx - mn;
    double w2 = (double)an2_w[tid];
    sE2D[tid] = exp(w2);
    sB2D[tid] = (double)an2_b[tid];
    sDimD[tid] = -w1 - log(mx - mn) - log1p(-c) - w2;
  }
  __syncthreads();

  for (int j = tid; j < KK; j += NT) {
    float acc = 0.f;
    #pragma unroll
    for (int d = 0; d < DD; ++d) { float a = sA[j][d]; acc = fmaf(a, a, acc); }
    sAsqH[j] = 0.5f * acc;
  }

  float lm = -3.4e38f;
  for (int i = tid; i < KK; i += NT) lm = fmaxf(lm, mlogits[i]);
  #pragma unroll
  for (int o = 32; o > 0; o >>= 1) lm = fmaxf(lm, __shfl_xor(lm, o));
  if (lane == 0) sPartD[sl] = (double)lm;
  __syncthreads();
  float gmax = (float)fmax(fmax(sPartD[0], sPartD[1]), fmax(sPartD[2], sPartD[3]));
  double lsum = 0.0;
  for (int i = tid; i < KK; i += NT) lsum += exp((double)mlogits[i] - (double)gmax);
  #pragma unroll
  for (int o = 32; o > 0; o >>= 1) lsum += __shfl_xor(lsum, o);
  if (lane == 0) sPartD[4 + sl] = lsum;
  __syncthreads();
  if (tid == 0) {
    double lse = (double)gmax + log(sPartD[4] + sPartD[5] + sPartD[6] + sPartD[7]);
    double b = (double)DD * (log(0.98) + log(1.0 + 2.0 * (0.01 / 0.98)));
    #pragma unroll
    for (int d = 0; d < DD; ++d) b += sDimD[d];
    sBaseD = b + lse;
  }

  double x4d[DD];
  double lsigD = 0.0;
  if (sl == 0) {
    const double A = 0.01, EPSB = 0.01 / 0.98;
    const double SPAN = 1.0 + 2.0 * EPSB;
    const float* xr = x_in + (size_t)row * DD;
    #pragma unroll
    for (int d = 0; d < DD; ++d) {
      double y1 = ((double)xr[d] + sB1D[d]) * sE1D[d];
      double sg = 1.0 / (1.0 + exp(-y1));
      double x2 = (sg - A) / (1.0 - 2.0 * A);
      double x3 = (x2 + EPSB) / SPAN;
      double x4 = x3 * sSclD[d] + sMnD[d];
      x4d[d] = x4;
      sX4T[d][lane] = (float)x4;
      double ay = fabs(y1);
      lsigD += ay + 2.0 * log1p(exp(-ay));
    }
  }
  {
    float4* mz = (float4*)(out + coreEnd + (size_t)blockIdx.x * RPB * KK);
    #pragma unroll 4
    for (int i = tid; i < RPB * KK / 4; i += NT)
      mz[i] = make_float4(0.f, 0.f, 0.f, 0.f);
  }
  __syncthreads();

  float x4f[DD];
  #pragma unroll
  for (int d = 0; d < DD; ++d) x4f[d] = sX4T[d][lane];

  float m1 = -3.4e38f, m2v = -3.4e38f;
  int j1 = 0x7fffffff, j2v = 0x7fffffff;
  const int jlo = sl * JSL4, jhi = jlo + JSL4;
  #pragma unroll 2
  for (int j = jlo; j < jhi; ++j) {
    float acc = -sAsqH[j];
    const float4* ar = (const float4*)&sA[j][0];
    #pragma unroll
    for (int dq = 0; dq < 4; ++dq) {
      float4 a4 = ar[dq];
      acc = fmaf(x4f[4 * dq + 0], a4.x, acc);
      acc = fmaf(x4f[4 * dq + 1], a4.y, acc);
      acc = fmaf(x4f[4 * dq + 2], a4.z, acc);
      acc = fmaf(x4f[4 * dq + 3], a4.w, acc);
    }
    bool gt1 = acc > m1;
    bool gt2 = acc > m2v;
    m2v = gt1 ? m1 : (gt2 ? acc : m2v);
    j2v = gt1 ? j1 : (gt2 ? j : j2v);
    m1  = gt1 ? acc : m1;
    j1  = gt1 ? j : j1;
  }
  sPj1[sl][lane] = j1;
  sPj2[sl][lane] = j2v;
  __syncthreads();

  if (sl == 0) {
    double best = 1e300; int bk = 0x7fffffff;
    #pragma unroll
    for (int ss = 0; ss < SLC4; ++ss) {
      #pragma unroll
      for (int t = 0; t < 2; ++t) {
        int j = t ? sPj2[ss][lane] : sPj1[ss][lane];
        double asq = 0.0, dot = 0.0;
        #pragma unroll
        for (int d = 0; d < DD; ++d) {
          double a = xformD((double)anchor_raw[j * DD + d], sMnD[d], sSclD[d]);
          asq = fma(a, a, asq);
          dot = fma(x4d[d], a, dot);
        }
        double d2 = asq - 2.0 * dot;
        if (d2 < best || (d2 == best && j < bk)) { best = d2; bk = j; }
      }
    }
    sKidx[lane] = bk;
  }
  __syncthreads();

  const int k = sKidx[lane];

  float akf[DD], dxf[DD];
  float r2f = 0.f, dxak = 0.f;
  #pragma unroll
  for (int d = 0; d < DD; ++d) {
    float a = sA[k][d];
    akf[d] = a;
    float dx = (float)sOmcD[d] * (x4f[d] - a);
    dxf[d] = dx;
    r2f  = fmaf(dx, dx, r2f);
    dxak = fmaf(dx, a, dxak);
  }
  const float epsr = 1e-12f * sqrtf(r2f);
  const float asqhk = sAsqH[k];

  float q1 = 0.f, h1 = 1.f, q2 = 0.f, h2 = 1.f;
  int i1 = -1, i2 = -1;
  #pragma unroll 2
  for (int j = jlo; j < jhi; ++j) {
    float q = -dxak;
    float h = asqhk + sAsqH[j];
    const float4* ar = (const float4*)&sA[j][0];
    #pragma unroll
    for (int dq = 0; dq < 4; ++dq) {
      float4 a4 = ar[dq];
      q = fmaf(dxf[4 * dq + 0], a4.x, q);
      q = fmaf(dxf[4 * dq + 1], a4.y, q);
      q = fmaf(dxf[4 * dq + 2], a4.z, q);
      q = fmaf(dxf[4 * dq + 3], a4.w, q);
      h = fmaf(-akf[4 * dq + 0], a4.x, h);
      h = fmaf(-akf[4 * dq + 1], a4.y, h);
      h = fmaf(-akf[4 * dq + 2], a4.z, h);
      h = fmaf(-akf[4 * dq + 3], a4.w, h);
    }
    bool valid = (j != k) & (q > epsr);
    bool b1 = valid && (q * h1 > q1 * h);
    bool b2 = valid && (q * h2 > q2 * h);
    float nq2 = b1 ? q1 : (b2 ? q : q2);
    float nh2 = b1 ? h1 : (b2 ? h : h2);
    int   ni2 = b1 ? i1 : (b2 ? j : i2);
    q1 = b1 ? q : q1; h1 = b1 ? h : h1; i1 = b1 ? j : i1;
    q2 = nq2; h2 = nh2; i2 = ni2;
  }
  sRI1[sl][lane] = i1;
  sRI2[sl][lane] = i2;
  __syncthreads();

  if (sl == 0) {
    double akD[DD], dxD[DD];
    double r2 = 0.0;
    #pragma unroll
    for (int d = 0; d < DD; ++d) {
      double a = xformD((double)anchor_raw[k * DD + d], sMnD[d], sSclD[d]);
      akD[d] = a;
      double dx = sOmcD[d] * (x4d[d] - a);
      dxD[d] = dx;
      r2 = fma(dx, dx, r2);
    }
    double rD = sqrt(r2);
    double rr = fmax(rD, 1e-12);
    double ratio = rD / 1e9;

    #pragma unroll
    for (int ss = 0; ss < SLC4; ++ss) {
      #pragma unroll
      for (int t = 0; t < 2; ++t) {
        int j = t ? sRI2[ss][lane] : sRI1[ss][lane];
        if (j < 0 || j == k) continue;
        double q = 0.0, h = 0.0;
        #pragma unroll
        for (int d = 0; d < DD; ++d) {
          double aj = xformD((double)anchor_raw[j * DD + d], sMnD[d], sSclD[d]);
          double g = aj - akD[d];
          q = fma(dxD[d], g, q);
          h = fma(g, g, h);
        }
        double proj = q / rr;
        if (proj > 1e-12) {
          double cand = rD * proj / (0.5 * h);
          ratio = fmax(ratio, cand);
        }
      }
    }
    #pragma unroll
    for (int d = 0; d < DD; ++d) {
      double u = dxD[d] / rr;
      if (u > 1e-12)        ratio = fmax(ratio, rD * u / (sMxD[d] - akD[d]));
      else if (u < -1e-12)  ratio = fmax(ratio, rD * u / (sMnD[d] - akD[d]));
    }

    double sS = 1.0 / (1.0 - ratio);
    float* xo = out + (size_t)row * DD;
    #pragma unroll
    for (int d = 0; d < DD; ++d) {
      double x7 = dxD[d] * sS;
      double x8 = (x7 + sB2D[d]) * sE2D[d];
      xo[d] = (float)x8;
    }
    double lp = (double)logp_in[row] + sBaseD + lsigD
              + 17.0 * log1p(-ratio)
              - (double)mlogits[k];
    out[(size_t)Brows * DD + row] = (float)lp;
    out[coreEnd + (size_t)row * KK + k] = 1.0f;
  }
}

extern "C" void kernel_launch(void* const* d_in, const int* in_sizes, int n_in,
                              void* d_out, int out_size, void* d_ws, size_t ws_size,
                              hipStream_t stream) {
  (void)n_in; (void)out_size;
  const float* x_in   = (const float*)d_in[0];
  const float* logp   = (const float*)d_in[1];
  const float* an1w   = (const float*)d_in[2];
  const float* an1b   = (const float*)d_in[3];
  const float* an2w   = (const float*)d_in[4];
  const float* an2b   = (const float*)d_in[5];
  const float* shiftc = (const float*)d_in[6];
  const float* anchor = (const float*)d_in[7];
  const float* bmin   = (const float*)d_in[8];
  const float* bmax   = (const float*)d_in[9];
  const float* mlog   = (const float*)d_in[10];
  const int B = in_sizes[0] / DD;

  if (ws_size >= (size_t)WS_NEED_BYTES && d_ws != nullptr && (B % RPB2) == 0) {
    double* ws = (double*)d_ws;
    hipLaunchKernelGGL(vor_pre, dim3(16), dim3(256), 0, stream,
                       an1w, an2w, an2b, shiftc, anchor, bmin, bmax, mlog, ws);
    hipLaunchKernelGGL(vor9, dim3(B / RPB2), dim3(NT2), 0, stream,
                       x_in, logp, an1b, mlog,
                       (const double*)ws, (float*)d_out, B);
  } else {
    hipLaunchKernelGGL(vor_green, dim3(B / RPB), dim3(NT), 0, stream,
                       x_in, logp, an1w, an1b, an2w, an2b, shiftc, anchor,
                       bmin, bmax, mlog, (float*)d_out, B);
  }
}

// Round 20
// 91.241 us; speedup vs baseline: 1.1439x; 1.0656x over previous
//
#include <hip/hip_runtime.h>
#include <math.h>

#define DD 16
#define KK 1024

typedef float f2 __attribute__((ext_vector_type(2)));

// ---- workspace layout (doubles) ----
#define WS_A    0
#define WS_ASQ  16384
#define WS_OMC  17408
#define WS_B2   17424
#define WS_E2   17440
#define WS_MN   17456
#define WS_MX   17472
#define WS_SCL  17488
#define WS_DIM  17504
#define WS_E1   17520
#define WS_BASE 17536
#define WS_TOTD 17537
#define WS_NEED_BYTES (WS_TOTD * 8)

__device__ __forceinline__ double xformD(double rv, double mn, double scl) {
  double t = rv / (1.0 + fabs(rv));
  return (t + 1.0) * 0.5 * scl + mn;
}
__device__ __forceinline__ float xformF(float v, float mn, float mx) {
  return (v / (1.f + fabsf(v)) + 1.f) * 0.5f * (mx - mn) + mn;
}

// =============== kernel A: precompute f64 tables into ws (proven) ===============
__global__ __launch_bounds__(256) void vor_pre(
    const float* __restrict__ an1_w, const float* __restrict__ an2_w,
    const float* __restrict__ an2_b, const float* __restrict__ shift_c,
    const float* __restrict__ anchor_raw,
    const float* __restrict__ box_min, const float* __restrict__ box_max,
    const float* __restrict__ mlogits, double* __restrict__ ws)
{
  __shared__ double redD[16];
  const int tid = threadIdx.x;
  const int blk = blockIdx.x;

  if (blk == 0 && tid < DD) {
    double w1 = (double)an1_w[tid], w2 = (double)an2_w[tid];
    double sgc = 1.0 / (1.0 + exp(-(double)shift_c[tid]));
    double c = sgc * 0.98 + 0.01;
    double mn = (double)box_min[tid], mx = (double)box_max[tid];
    ws[WS_OMC + tid] = 1.0 - c;
    ws[WS_B2  + tid] = (double)an2_b[tid];
    ws[WS_E2  + tid] = exp(w2);
    ws[WS_MN  + tid] = mn;
    ws[WS_MX  + tid] = mx;
    ws[WS_SCL + tid] = mx - mn;
    ws[WS_E1  + tid] = exp(w1);
    ws[WS_DIM + tid] = -w1 - log(mx - mn) - log1p(-c) - w2;
  }
  const int j0 = blk * 64;
  for (int e = tid; e < 64 * DD; e += 256) {
    int j = j0 + (e >> 4), d = e & 15;
    double mn = (double)box_min[d];
    double scl = (double)box_max[d] - mn;
    ws[WS_A + (size_t)j * DD + d] = xformD((double)anchor_raw[j * DD + d], mn, scl);
  }
  __syncthreads();
  for (int j = j0 + tid; j < j0 + 64; j += 256) {
    double s = 0.0;
    #pragma unroll
    for (int d = 0; d < DD; ++d) { double a = ws[WS_A + (size_t)j * DD + d]; s = fma(a, a, s); }
    ws[WS_ASQ + j] = s;
  }
  if (blk != 0) return;
  float lm = -3.4e38f;
  for (int i = tid; i < KK; i += 256) lm = fmaxf(lm, mlogits[i]);
  #pragma unroll
  for (int o = 32; o > 0; o >>= 1) lm = fmaxf(lm, __shfl_xor(lm, o));
  if ((tid & 63) == 0) redD[tid >> 6] = (double)lm;
  __syncthreads();
  float gmax = (float)fmax(fmax(redD[0], redD[1]), fmax(redD[2], redD[3]));
  double lsum = 0.0;
  for (int i = tid; i < KK; i += 256) lsum += exp((double)mlogits[i] - (double)gmax);
  #pragma unroll
  for (int o = 32; o > 0; o >>= 1) lsum += __shfl_xor(lsum, o);
  if ((tid & 63) == 0) redD[4 + (tid >> 6)] = lsum;
  __syncthreads();
  if (tid == 0) {
    double lse = (double)gmax + log(redD[4] + redD[5] + redD[6] + redD[7]);
    double b = (double)DD * (log(0.98) + log(1.0 + 2.0 * (0.01 / 0.98)));
    #pragma unroll
    for (int d = 0; d < DD; ++d) b += ws[WS_DIM + d];
    ws[WS_BASE] = b + lse;
  }
}

// =============== kernel B: vor9 with mask-zero issue moved into sweep-1 phase ===============
#define NT2 1024
#define RPB2 128
#define SL2 8            // sweep-2 slices (128 j)
#define JSL2 (KK / SL2)
#define NS1 16           // sweep-1 slices (64 j)
#define JS1 (KK / NS1)

__global__ __launch_bounds__(NT2, 4) void vor10(
    const float* __restrict__ x_in, const float* __restrict__ logp_in,
    const float* __restrict__ an1_b,
    const float* __restrict__ mlogits, const double* __restrict__ ws,
    float* __restrict__ out, int Brows)
{
  __shared__ __align__(16) float sAp[KK][DD];  // 64 KB anchors, pair-permuted {0,8,1,9,...}
  __shared__ float  sAsqH[KK];                 // 4 KB
  __shared__ double sX4D[DD][RPB2];            // 16 KB f64 x4
  __shared__ float  sLT[DD][RPB2];             // 8 KB lsig terms
  __shared__ double sD2[NS1][RPB2];            // 16 KB refined d2 per (slice16,row)
  __shared__ int    sJJ[NS1][RPB2];            // 8 KB refined j
  __shared__ float  sRat[16][64];              // 4 KB ratio cand per (wave,lane)
  __shared__ float  sOmcF[DD], sB2F[DD], sE2F[DD], sMnF[DD], sMxF[DD];

  const int tid  = threadIdx.x;
  const int w    = tid >> 6;        // 0..15
  const int lane = tid & 63;
  const int rg   = w >> 3;          // sweep-2 row-group
  const int sl   = w & 7;           // sweep-2 slice
  const int rrow = rg * 64 + lane;  // this wave's own row (sweep 2 / epilogue)
  const int r0   = lane, r1 = lane + 64;   // sweep-1 paired rows
  const int row  = blockIdx.x * RPB2 + rrow;
  const size_t coreEnd = (size_t)Brows * (DD + 1);

  if (tid < DD) {
    sOmcF[tid] = (float)ws[WS_OMC + tid];
    sB2F[tid]  = (float)ws[WS_B2 + tid];
    sE2F[tid]  = (float)ws[WS_E2 + tid];
    sMnF[tid]  = (float)ws[WS_MN + tid];
    sMxF[tid]  = (float)ws[WS_MX + tid];
  }
  // stage anchors pair-permuted from f64 ws (proven provenance)
  for (int e = tid; e < KK * DD; e += NT2) {
    int j = e >> 4, d = e & 15;
    float v = (float)ws[WS_A + (size_t)j * DD + d];
    int pos = (d < 8) ? (2 * d) : (2 * (d - 8) + 1);
    sAp[j][pos] = v;
  }
  // f64 x4 chain distributed (2 elems/thread)
  {
    const double A = 0.01, EPSB = 0.01 / 0.98;
    const double SPAN = 1.0 + 2.0 * EPSB;
    const float* xb = x_in + (size_t)blockIdx.x * RPB2 * DD;
    for (int e = tid; e < RPB2 * DD; e += NT2) {
      int rr = e >> 4, d = e & 15;
      double y1 = ((double)xb[e] + (double)an1_b[d]) * ws[WS_E1 + d];
      double sg = 1.0 / (1.0 + exp(-y1));
      double x2 = (sg - A) / (1.0 - 2.0 * A);
      double x3 = (x2 + EPSB) / SPAN;
      double x4 = x3 * ws[WS_SCL + d] + ws[WS_MN + d];
      sX4D[d][rr] = x4;
      double ay = fabs(y1);
      sLT[d][rr] = (float)(ay + 2.0 * log1p(exp(-ay)));
    }
  }
  __syncthreads();     // barrier A: sAp, sX4D, sLT ready (NO mask stores to drain here)

  // asqH: natural-order f32 fmaf chain from permuted storage (proven provenance)
  for (int j = tid; j < KK; j += NT2) {
    float a[DD];
    #pragma unroll
    for (int i = 0; i < 8; ++i) { a[i] = sAp[j][2 * i]; a[i + 8] = sAp[j][2 * i + 1]; }
    float acc = 0.f;
    #pragma unroll
    for (int d = 0; d < DD; ++d) acc = fmaf(a[d], a[d], acc);
    sAsqH[j] = 0.5f * acc;
  }

  // paired x4 for sweep 1
  f2 xp0[8], xp1[8];
  #pragma unroll
  for (int i = 0; i < 8; ++i) {
    xp0[i] = (f2){(float)sX4D[i][r0], (float)sX4D[i + 8][r0]};
    xp1[i] = (f2){(float)sX4D[i][r1], (float)sX4D[i + 8][r1]};
  }
  __syncthreads();     // barrier B: sAsqH ready

  // ---- zero this block's f32 mask stripe: ISSUED HERE so the vmcnt(0) drain at
  //      barrier C overlaps the sweep-1 compute (~30us) instead of stalling barrier A ----
  {
    float4* mz = (float4*)(out + coreEnd + (size_t)blockIdx.x * RPB2 * KK);
    #pragma unroll 4
    for (int i = tid; i < RPB2 * KK / 4; i += NT2)
      mz[i] = make_float4(0.f, 0.f, 0.f, 0.f);
  }

  // ---- sweep 1 (paired pk, 16 slices of 64): top-2 per row ----
  {
    const int jlo = w * JS1, jhi = jlo + JS1;
    float m1_0 = -3.4e38f, m2_0 = -3.4e38f; int j1_0 = jlo, j2_0 = jlo;
    float m1_1 = -3.4e38f, m2_1 = -3.4e38f; int j1_1 = jlo, j2_1 = jlo;
    #pragma unroll 4
    for (int j = jlo; j < jhi; ++j) {
      const float4* ar = (const float4*)&sAp[j][0];
      float4 A0 = ar[0], A1 = ar[1], A2 = ar[2], A3 = ar[3];
      f2 p0 = (f2){A0.x, A0.y}, p1 = (f2){A0.z, A0.w};
      f2 p2 = (f2){A1.x, A1.y}, p3 = (f2){A1.z, A1.w};
      f2 p4 = (f2){A2.x, A2.y}, p5 = (f2){A2.z, A2.w};
      f2 p6 = (f2){A3.x, A3.y}, p7 = (f2){A3.z, A3.w};
      float nq = -sAsqH[j];
      f2 a0 = (f2){nq, 0.f}, a1 = (f2){nq, 0.f};
      a0 = __builtin_elementwise_fma(xp0[0], p0, a0); a1 = __builtin_elementwise_fma(xp1[0], p0, a1);
      a0 = __builtin_elementwise_fma(xp0[1], p1, a0); a1 = __builtin_elementwise_fma(xp1[1], p1, a1);
      a0 = __builtin_elementwise_fma(xp0[2], p2, a0); a1 = __builtin_elementwise_fma(xp1[2], p2, a1);
      a0 = __builtin_elementwise_fma(xp0[3], p3, a0); a1 = __builtin_elementwise_fma(xp1[3], p3, a1);
      a0 = __builtin_elementwise_fma(xp0[4], p4, a0); a1 = __builtin_elementwise_fma(xp1[4], p4, a1);
      a0 = __builtin_elementwise_fma(xp0[5], p5, a0); a1 = __builtin_elementwise_fma(xp1[5], p5, a1);
      a0 = __builtin_elementwise_fma(xp0[6], p6, a0); a1 = __builtin_elementwise_fma(xp1[6], p6, a1);
      a0 = __builtin_elementwise_fma(xp0[7], p7, a0); a1 = __builtin_elementwise_fma(xp1[7], p7, a1);
      float s0 = a0.x + a0.y, s1 = a1.x + a1.y;
      bool g1 = s0 > m1_0, g2 = s0 > m2_0;
      m2_0 = g1 ? m1_0 : (g2 ? s0 : m2_0);
      j2_0 = g1 ? j1_0 : (g2 ? j : j2_0);
      m1_0 = g1 ? s0 : m1_0;
      j1_0 = g1 ? j : j1_0;
      bool h1b = s1 > m1_1, h2b = s1 > m2_1;
      m2_1 = h1b ? m1_1 : (h2b ? s1 : m2_1);
      j2_1 = h1b ? j1_1 : (h2b ? j : j2_1);
      m1_1 = h1b ? s1 : m1_1;
      j1_1 = h1b ? j : j1_1;
    }
    // f64 refine both rows' top-2
    {
      double bD = 1e300; int bk = 0x7fffffff;
      #pragma unroll
      for (int t = 0; t < 2; ++t) {
        int j = t ? j2_0 : j1_0;
        const double* aj = ws + WS_A + (size_t)j * DD;
        double dot = 0.0;
        #pragma unroll
        for (int d = 0; d < DD; ++d) dot = fma(sX4D[d][r0], aj[d], dot);
        double d2 = ws[WS_ASQ + j] - 2.0 * dot;
        if (d2 < bD || (d2 == bD && j < bk)) { bD = d2; bk = j; }
      }
      sD2[w][r0] = bD; sJJ[w][r0] = bk;
    }
    {
      double bD = 1e300; int bk = 0x7fffffff;
      #pragma unroll
      for (int t = 0; t < 2; ++t) {
        int j = t ? j2_1 : j1_1;
        const double* aj = ws + WS_A + (size_t)j * DD;
        double dot = 0.0;
        #pragma unroll
        for (int d = 0; d < DD; ++d) dot = fma(sX4D[d][r1], aj[d], dot);
        double d2 = ws[WS_ASQ + j] - 2.0 * dot;
        if (d2 < bD || (d2 == bD && j < bk)) { bD = d2; bk = j; }
      }
      sD2[w][r1] = bD; sJJ[w][r1] = bk;
    }
  }
  __syncthreads();     // barrier C: drains mask stores, fully overlapped with sweep 1

  // combine k for OWN row across 16 slices (deterministic)
  int k = 0x7fffffff;
  {
    double kb = 1e300;
    #pragma unroll
    for (int ss = 0; ss < NS1; ++ss) {
      double d = sD2[ss][rrow];
      int    j = sJJ[ss][rrow];
      if (d < kb || (d == kb && j < k)) { kb = d; k = j; }
    }
  }

  // ---- sweep 2 setup (own row) ----
  float x4f[DD];
  #pragma unroll
  for (int d = 0; d < DD; ++d) x4f[d] = (float)sX4D[d][rrow];
  float akf[DD];
  {
    const float4* akp = (const float4*)&sAp[k][0];
    float4 K0 = akp[0], K1 = akp[1], K2 = akp[2], K3 = akp[3];
    akf[0] = K0.x; akf[8]  = K0.y; akf[1] = K0.z; akf[9]  = K0.w;
    akf[2] = K1.x; akf[10] = K1.y; akf[3] = K1.z; akf[11] = K1.w;
    akf[4] = K2.x; akf[12] = K2.y; akf[5] = K2.z; akf[13] = K2.w;
    akf[6] = K3.x; akf[14] = K3.y; akf[7] = K3.z; akf[15] = K3.w;
  }
  float dxf[DD];
  float r2f = 0.f, dxak = 0.f;
  #pragma unroll
  for (int d = 0; d < DD; ++d) {
    float dx = sOmcF[d] * (x4f[d] - akf[d]);
    dxf[d] = dx;
    r2f  = fmaf(dx, dx, r2f);
    dxak = fmaf(dx, akf[d], dxak);
  }
  const float rf   = sqrtf(r2f);
  const float rrf  = fmaxf(rf, 1e-12f);
  const float scal = rf / rrf;
  const float epsr = 1e-12f * rf;
  const float asqhk = sAsqH[k];

  f2 dx2[8], nak2[8];
  #pragma unroll
  for (int i = 0; i < 8; ++i) {
    dx2[i]  = (f2){dxf[i], dxf[i + 8]};
    nak2[i] = (f2){-akf[i], -akf[i + 8]};
  }

  // ---- sweep 2 (pk f32, 8 slices of 128) ----
  float q1 = 0.f, h1 = 1.f;
  const int jlo2 = sl * JSL2, jhi2 = jlo2 + JSL2;
  #pragma unroll 4
  for (int j = jlo2; j < jhi2; ++j) {
    const float4* ar = (const float4*)&sAp[j][0];
    float4 A0 = ar[0], A1 = ar[1], A2 = ar[2], A3 = ar[3];
    f2 p0 = (f2){A0.x, A0.y}, p1 = (f2){A0.z, A0.w};
    f2 p2 = (f2){A1.x, A1.y}, p3 = (f2){A1.z, A1.w};
    f2 p4 = (f2){A2.x, A2.y}, p5 = (f2){A2.z, A2.w};
    f2 p6 = (f2){A3.x, A3.y}, p7 = (f2){A3.z, A3.w};
    f2 q2 = (f2){-dxak, 0.f};
    f2 h2 = (f2){asqhk + sAsqH[j], 0.f};
    q2 = __builtin_elementwise_fma(dx2[0], p0, q2); h2 = __builtin_elementwise_fma(nak2[0], p0, h2);
    q2 = __builtin_elementwise_fma(dx2[1], p1, q2); h2 = __builtin_elementwise_fma(nak2[1], p1, h2);
    q2 = __builtin_elementwise_fma(dx2[2], p2, q2); h2 = __builtin_elementwise_fma(nak2[2], p2, h2);
    q2 = __builtin_elementwise_fma(dx2[3], p3, q2); h2 = __builtin_elementwise_fma(nak2[3], p3, h2);
    q2 = __builtin_elementwise_fma(dx2[4], p4, q2); h2 = __builtin_elementwise_fma(nak2[4], p4, h2);
    q2 = __builtin_elementwise_fma(dx2[5], p5, q2); h2 = __builtin_elementwise_fma(nak2[5], p5, h2);
    q2 = __builtin_elementwise_fma(dx2[6], p6, q2); h2 = __builtin_elementwise_fma(nak2[6], p6, h2);
    q2 = __builtin_elementwise_fma(dx2[7], p7, q2); h2 = __builtin_elementwise_fma(nak2[7], p7, h2);
    float q = q2.x + q2.y, h = h2.x + h2.y;
    bool upd = (j != k) & (q > epsr) & (q * h1 > q1 * h);
    q1 = upd ? q : q1;
    h1 = upd ? h : h1;
  }
  sRat[w][lane] = scal * (q1 / h1);
  __syncthreads();     // barrier D

  // ---- epilogue waves (sl==0, one per rg): combine ratio, box faces, outputs ----
  if (sl == 0) {
    float ratio = rf * 1e-9f;
    #pragma unroll
    for (int ss = 0; ss < SL2; ++ss) ratio = fmaxf(ratio, sRat[rg * 8 + ss][lane]);
    #pragma unroll
    for (int d = 0; d < DD; ++d) {
      float uf = dxf[d] / rrf;
      if (uf > 1e-12f)        ratio = fmaxf(ratio, rf * uf / (sMxF[d] - akf[d]));
      else if (uf < -1e-12f)  ratio = fmaxf(ratio, rf * uf / (sMnF[d] - akf[d]));
    }
    float sS = 1.0f / (1.0f - ratio);
    float xo[DD];
    float lsig = 0.f;
    #pragma unroll
    for (int d = 0; d < DD; ++d) {
      xo[d] = (dxf[d] * sS + sB2F[d]) * sE2F[d];
      lsig += sLT[d][rrow];
    }
    float4* xp = (float4*)(out + (size_t)row * DD);
    xp[0] = make_float4(xo[0], xo[1], xo[2], xo[3]);
    xp[1] = make_float4(xo[4], xo[5], xo[6], xo[7]);
    xp[2] = make_float4(xo[8], xo[9], xo[10], xo[11]);
    xp[3] = make_float4(xo[12], xo[13], xo[14], xo[15]);
    double lp = (double)logp_in[row] + ws[WS_BASE] + (double)lsig
              + 17.0 * log1p(-(double)ratio)
              - (double)mlogits[k];
    out[(size_t)Brows * DD + row] = (float)lp;
    out[coreEnd + (size_t)row * KK + k] = 1.0f;
  }
}

// =============== fallback: round-6 green kernel (unchanged) ===============
#define NT 256
#define RPB 64
#define SLC4 4
#define JSL4 (KK / SLC4)

__global__ __launch_bounds__(NT, 2) void vor_green(
    const float* __restrict__ x_in, const float* __restrict__ logp_in,
    const float* __restrict__ an1_w, const float* __restrict__ an1_b,
    const float* __restrict__ an2_w, const float* __restrict__ an2_b,
    const float* __restrict__ shift_c, const float* __restrict__ anchor_raw,
    const float* __restrict__ box_min, const float* __restrict__ box_max,
    const float* __restrict__ mlogits,
    float* __restrict__ out, int Brows)
{
  __shared__ __align__(16) float sA[KK][DD];
  __shared__ float  sAsqH[KK];
  __shared__ float  sX4T[DD][RPB];
  __shared__ int    sPj1[SLC4][RPB], sPj2[SLC4][RPB];
  __shared__ int    sRI1[SLC4][RPB], sRI2[SLC4][RPB];
  __shared__ double sPartD[8];
  __shared__ double sE1D[DD], sB1D[DD], sOmcD[DD], sB2D[DD], sE2D[DD];
  __shared__ double sMnD[DD], sMxD[DD], sSclD[DD], sDimD[DD];
  __shared__ double sBaseD;
  __shared__ int    sKidx[RPB];

  const int tid  = threadIdx.x;
  const int sl   = tid >> 6;
  const int lane = tid & 63;
  const int row  = blockIdx.x * RPB + lane;
  const size_t coreEnd = (size_t)Brows * (DD + 1);

  for (int e = tid; e < KK * DD / 4; e += NT) {
    float4 raw = ((const float4*)anchor_raw)[e];
    float4 bmn = ((const float4*)box_min)[e & 3];
    float4 bmx = ((const float4*)box_max)[e & 3];
    float4 o;
    o.x = xformF(raw.x, bmn.x, bmx.x);
    o.y = xformF(raw.y, bmn.y, bmx.y);
    o.z = xformF(raw.z, bmn.z, bmx.z);
    o.w = xformF(raw.w, bmn.w, bmx.w);
    ((float4*)sA)[e] = o;
  }
  if (tid < DD) {
    double w1 = (double)an1_w[tid];
    sE1D[tid] = exp(w1);
    sB1D[tid] = (double)an1_b[tid];
    double sgc = 1.0 / (1.0 + exp(-(double)shift_c[tid]));
    double c = sgc * 0.98 + 0.01;
    sOmcD[tid] = 1.0 - c;
    double mn = (double)box_min[tid], mx = (double)box_max[tid];
    sMnD[tid] = mn; sMxD[tid] = mx; sSclD[tid] = mx - mn;
    double w2 = (double)an2_w[tid];
    sE2D[tid] = exp(w2);
    sB2D[tid] = (double)an2_b[tid];
    sDimD[tid] = -w1 - log(mx - mn) - log1p(-c) - w2;
  }
  __syncthreads();

  for (int j = tid; j < KK; j += NT) {
    float acc = 0.f;
    #pragma unroll
    for (int d = 0; d < DD; ++d) { float a = sA[j][d]; acc = fmaf(a, a, acc); }
    sAsqH[j] = 0.5f * acc;
  }

  float lm = -3.4e38f;
  for (int i = tid; i < KK; i += NT) lm = fmaxf(lm, mlogits[i]);
  #pragma unroll
  for (int o = 32; o > 0; o >>= 1) lm = fmaxf(lm, __shfl_xor(lm, o));
  if (lane == 0) sPartD[sl] = (double)lm;
  __syncthreads();
  float gmax = (float)fmax(fmax(sPartD[0], sPartD[1]), fmax(sPartD[2], sPartD[3]));
  double lsum = 0.0;
  for (int i = tid; i < KK; i += NT) lsum += exp((double)mlogits[i] - (double)gmax);
  #pragma unroll
  for (int o = 32; o > 0; o >>= 1) lsum += __shfl_xor(lsum, o);
  if (lane == 0) sPartD[4 + sl] = lsum;
  __syncthreads();
  if (tid == 0) {
    double lse = (double)gmax + log(sPartD[4] + sPartD[5] + sPartD[6] + sPartD[7]);
    double b = (double)DD * (log(0.98) + log(1.0 + 2.0 * (0.01 / 0.98)));
    #pragma unroll
    for (int d = 0; d < DD; ++d) b += sDimD[d];
    sBaseD = b + lse;
  }

  double x4d[DD];
  double lsigD = 0.0;
  if (sl == 0) {
    const double A = 0.01, EPSB = 0.01 / 0.98;
    const double SPAN = 1.0 + 2.0 * EPSB;
    const float* xr = x_in + (size_t)row * DD;
    #pragma unroll
    for (int d = 0; d < DD; ++d) {
      double y1 = ((double)xr[d] + sB1D[d]) * sE1D[d];
      double sg = 1.0 / (1.0 + exp(-y1));
      double x2 = (sg - A) / (1.0 - 2.0 * A);
      double x3 = (x2 + EPSB) / SPAN;
      double x4 = x3 * sSclD[d] + sMnD[d];
      x4d[d] = x4;
      sX4T[d][lane] = (float)x4;
      double ay = fabs(y1);
      lsigD += ay + 2.0 * log1p(exp(-ay));
    }
  }
  {
    float4* mz = (float4*)(out + coreEnd + (size_t)blockIdx.x * RPB * KK);
    #pragma unroll 4
    for (int i = tid; i < RPB * KK / 4; i += NT)
      mz[i] = make_float4(0.f, 0.f, 0.f, 0.f);
  }
  __syncthreads();

  float x4f[DD];
  #pragma unroll
  for (int d = 0; d < DD; ++d) x4f[d] = sX4T[d][lane];

  float m1 = -3.4e38f, m2v = -3.4e38f;
  int j1 = 0x7fffffff, j2v = 0x7fffffff;
  const int jlo = sl * JSL4, jhi = jlo + JSL4;
  #pragma unroll 2
  for (int j = jlo; j < jhi; ++j) {
    float acc = -sAsqH[j];
    const float4* ar = (const float4*)&sA[j][0];
    #pragma unroll
    for (int dq = 0; dq < 4; ++dq) {
      float4 a4 = ar[dq];
      acc = fmaf(x4f[4 * dq + 0], a4.x, acc);
      acc = fmaf(x4f[4 * dq + 1], a4.y, acc);
      acc = fmaf(x4f[4 * dq + 2], a4.z, acc);
      acc = fmaf(x4f[4 * dq + 3], a4.w, acc);
    }
    bool gt1 = acc > m1;
    bool gt2 = acc > m2v;
    m2v = gt1 ? m1 : (gt2 ? acc : m2v);
    j2v = gt1 ? j1 : (gt2 ? j : j2v);
    m1  = gt1 ? acc : m1;
    j1  = gt1 ? j : j1;
  }
  sPj1[sl][lane] = j1;
  sPj2[sl][lane] = j2v;
  __syncthreads();

  if (sl == 0) {
    double best = 1e300; int bk = 0x7fffffff;
    #pragma unroll
    for (int ss = 0; ss < SLC4; ++ss) {
      #pragma unroll
      for (int t = 0; t < 2; ++t) {
        int j = t ? sPj2[ss][lane] : sPj1[ss][lane];
        double asq = 0.0, dot = 0.0;
        #pragma unroll
        for (int d = 0; d < DD; ++d) {
          double a = xformD((double)anchor_raw[j * DD + d], sMnD[d], sSclD[d]);
          asq = fma(a, a, asq);
          dot = fma(x4d[d], a, dot);
        }
        double d2 = asq - 2.0 * dot;
        if (d2 < best || (d2 == best && j < bk)) { best = d2; bk = j; }
      }
    }
    sKidx[lane] = bk;
  }
  __syncthreads();

  const int k = sKidx[lane];

  float akf[DD], dxf[DD];
  float r2f = 0.f, dxak = 0.f;
  #pragma unroll
  for (int d = 0; d < DD; ++d) {
    float a = sA[k][d];
    akf[d] = a;
    float dx = (float)sOmcD[d] * (x4f[d] - a);
    dxf[d] = dx;
    r2f  = fmaf(dx, dx, r2f);
    dxak = fmaf(dx, a, dxak);
  }
  const float epsr = 1e-12f * sqrtf(r2f);
  const float asqhk = sAsqH[k];

  float q1 = 0.f, h1 = 1.f, q2 = 0.f, h2 = 1.f;
  int i1 = -1, i2 = -1;
  #pragma unroll 2
  for (int j = jlo; j < jhi; ++j) {
    float q = -dxak;
    float h = asqhk + sAsqH[j];
    const float4* ar = (const float4*)&sA[j][0];
    #pragma unroll
    for (int dq = 0; dq < 4; ++dq) {
      float4 a4 = ar[dq];
      q = fmaf(dxf[4 * dq + 0], a4.x, q);
      q = fmaf(dxf[4 * dq + 1], a4.y, q);
      q = fmaf(dxf[4 * dq + 2], a4.z, q);
      q = fmaf(dxf[4 * dq + 3], a4.w, q);
      h = fmaf(-akf[4 * dq + 0], a4.x, h);
      h = fmaf(-akf[4 * dq + 1], a4.y, h);
      h = fmaf(-akf[4 * dq + 2], a4.z, h);
      h = fmaf(-akf[4 * dq + 3], a4.w, h);
    }
    bool valid = (j != k) & (q > epsr);
    bool b1 = valid && (q * h1 > q1 * h);
    bool b2 = valid && (q * h2 > q2 * h);
    float nq2 = b1 ? q1 : (b2 ? q : q2);
    float nh2 = b1 ? h1 : (b2 ? h : h2);
    int   ni2 = b1 ? i1 : (b2 ? j : i2);
    q1 = b1 ? q : q1; h1 = b1 ? h : h1; i1 = b1 ? j : i1;
    q2 = nq2; h2 = nh2; i2 = ni2;
  }
  sRI1[sl][lane] = i1;
  sRI2[sl][lane] = i2;
  __syncthreads();

  if (sl == 0) {
    double akD[DD], dxD[DD];
    double r2 = 0.0;
    #pragma unroll
    for (int d = 0; d < DD; ++d) {
      double a = xformD((double)anchor_raw[k * DD + d], sMnD[d], sSclD[d]);
      akD[d] = a;
      double dx = sOmcD[d] * (x4d[d] - a);
      dxD[d] = dx;
      r2 = fma(dx, dx, r2);
    }
    double rD = sqrt(r2);
    double rr = fmax(rD, 1e-12);
    double ratio = rD / 1e9;

    #pragma unroll
    for (int ss = 0; ss < SLC4; ++ss) {
      #pragma unroll
      for (int t = 0; t < 2; ++t) {
        int j = t ? sRI2[ss][lane] : sRI1[ss][lane];
        if (j < 0 || j == k) continue;
        double q = 0.0, h = 0.0;
        #pragma unroll
        for (int d = 0; d < DD; ++d) {
          double aj = xformD((double)anchor_raw[j * DD + d], sMnD[d], sSclD[d]);
          double g = aj - akD[d];
          q = fma(dxD[d], g, q);
          h = fma(g, g, h);
        }
        double proj = q / rr;
        if (proj > 1e-12) {
          double cand = rD * proj / (0.5 * h);
          ratio = fmax(ratio, cand);
        }
      }
    }
    #pragma unroll
    for (int d = 0; d < DD; ++d) {
      double u = dxD[d] / rr;
      if (u > 1e-12)        ratio = fmax(ratio, rD * u / (sMxD[d] - akD[d]));
      else if (u < -1e-12)  ratio = fmax(ratio, rD * u / (sMnD[d] - akD[d]));
    }

    double sS = 1.0 / (1.0 - ratio);
    float* xo = out + (size_t)row * DD;
    #pragma unroll
    for (int d = 0; d < DD; ++d) {
      double x7 = dxD[d] * sS;
      double x8 = (x7 + sB2D[d]) * sE2D[d];
      xo[d] = (float)x8;
    }
    double lp = (double)logp_in[row] + sBaseD + lsigD
              + 17.0 * log1p(-ratio)
              - (double)mlogits[k];
    out[(size_t)Brows * DD + row] = (float)lp;
    out[coreEnd + (size_t)row * KK + k] = 1.0f;
  }
}

extern "C" void kernel_launch(void* const* d_in, const int* in_sizes, int n_in,
                              void* d_out, int out_size, void* d_ws, size_t ws_size,
                              hipStream_t stream) {
  (void)n_in; (void)out_size;
  const float* x_in   = (const float*)d_in[0];
  const float* logp   = (const float*)d_in[1];
  const float* an1w   = (const float*)d_in[2];
  const float* an1b   = (const float*)d_in[3];
  const float* an2w   = (const float*)d_in[4];
  const float* an2b   = (const float*)d_in[5];
  const float* shiftc = (const float*)d_in[6];
  const float* anchor = (const float*)d_in[7];
  const float* bmin   = (const float*)d_in[8];
  const float* bmax   = (const float*)d_in[9];
  const float* mlog   = (const float*)d_in[10];
  const int B = in_sizes[0] / DD;

  if (ws_size >= (size_t)WS_NEED_BYTES && d_ws != nullptr && (B % RPB2) == 0) {
    double* ws = (double*)d_ws;
    hipLaunchKernelGGL(vor_pre, dim3(16), dim3(256), 0, stream,
                       an1w, an2w, an2b, shiftc, anchor, bmin, bmax, mlog, ws);
    hipLaunchKernelGGL(vor10, dim3(B / RPB2), dim3(NT2), 0, stream,
                       x_in, logp, an1b, mlog,
                       (const double*)ws, (float*)d_out, B);
  } else {
    hipLaunchKernelGGL(vor_green, dim3(B / RPB), dim3(NT), 0, stream,
                       x_in, logp, an1w, an1b, an2w, an2b, shiftc, anchor,
                       bmin, bmax, mlog, (float*)d_out, B);
  }
}

// Round 21
// 89.182 us; speedup vs baseline: 1.1703x; 1.0231x over previous
//
#include <hip/hip_runtime.h>
#include <math.h>

#define DD 16
#define KK 1024

typedef float f2 __attribute__((ext_vector_type(2)));

// ---- workspace layout (doubles) ----
#define WS_A    0
#define WS_ASQ  16384
#define WS_OMC  17408
#define WS_B2   17424
#define WS_E2   17440
#define WS_MN   17456
#define WS_MX   17472
#define WS_SCL  17488
#define WS_DIM  17504
#define WS_E1   17520
#define WS_BASE 17536
#define WS_AFP  17538             // pair-permuted f32 anchors [1024][16] (8192 dbl, 16B-aligned)
#define WS_ASQF 25730             // f32 0.5*||a||^2 [1024] (512 dbl)
#define WS_TOTD 26242
#define WS_NEED_BYTES (WS_TOTD * 8)

__device__ __forceinline__ double xformD(double rv, double mn, double scl) {
  double t = rv / (1.0 + fabs(rv));
  return (t + 1.0) * 0.5 * scl + mn;
}
__device__ __forceinline__ float xformF(float v, float mn, float mx) {
  return (v / (1.f + fabsf(v)) + 1.f) * 0.5f * (mx - mn) + mn;
}

// =============== kernel A: precompute f64 + permuted f32 tables ===============
__global__ __launch_bounds__(256) void vor_pre(
    const float* __restrict__ an1_w, const float* __restrict__ an2_w,
    const float* __restrict__ an2_b, const float* __restrict__ shift_c,
    const float* __restrict__ anchor_raw,
    const float* __restrict__ box_min, const float* __restrict__ box_max,
    const float* __restrict__ mlogits, double* __restrict__ ws)
{
  __shared__ double redD[16];
  const int tid = threadIdx.x;
  const int blk = blockIdx.x;
  float* aFp   = (float*)(ws + WS_AFP);
  float* asqHF = (float*)(ws + WS_ASQF);

  if (blk == 0 && tid < DD) {
    double w1 = (double)an1_w[tid], w2 = (double)an2_w[tid];
    double sgc = 1.0 / (1.0 + exp(-(double)shift_c[tid]));
    double c = sgc * 0.98 + 0.01;
    double mn = (double)box_min[tid], mx = (double)box_max[tid];
    ws[WS_OMC + tid] = 1.0 - c;
    ws[WS_B2  + tid] = (double)an2_b[tid];
    ws[WS_E2  + tid] = exp(w2);
    ws[WS_MN  + tid] = mn;
    ws[WS_MX  + tid] = mx;
    ws[WS_SCL + tid] = mx - mn;
    ws[WS_E1  + tid] = exp(w1);
    ws[WS_DIM + tid] = -w1 - log(mx - mn) - log1p(-c) - w2;
  }
  const int j0 = blk * 64;
  for (int e = tid; e < 64 * DD; e += 256) {
    int j = j0 + (e >> 4), d = e & 15;
    double mn = (double)box_min[d];
    double scl = (double)box_max[d] - mn;
    ws[WS_A + (size_t)j * DD + d] = xformD((double)anchor_raw[j * DD + d], mn, scl);
  }
  __syncthreads();
  for (int j = j0 + tid; j < j0 + 64; j += 256) {
    double s = 0.0;
    float af[DD];
    float accf = 0.f;
    #pragma unroll
    for (int d = 0; d < DD; ++d) {
      double a = ws[WS_A + (size_t)j * DD + d];
      s = fma(a, a, s);
      af[d] = (float)a;                    // exact downcast the kernels used
      accf = fmaf(af[d], af[d], accf);     // exact natural-order fmaf chain
    }
    ws[WS_ASQ + j] = s;
    asqHF[j] = 0.5f * accf;
    #pragma unroll
    for (int d = 0; d < DD; ++d) {
      int pos = (d < 8) ? (2 * d) : (2 * (d - 8) + 1);
      aFp[j * DD + pos] = af[d];           // pair-permuted {0,8,1,9,...,7,15}
    }
  }
  if (blk != 0) return;
  float lm = -3.4e38f;
  for (int i = tid; i < KK; i += 256) lm = fmaxf(lm, mlogits[i]);
  #pragma unroll
  for (int o = 32; o > 0; o >>= 1) lm = fmaxf(lm, __shfl_xor(lm, o));
  if ((tid & 63) == 0) redD[tid >> 6] = (double)lm;
  __syncthreads();
  float gmax = (float)fmax(fmax(redD[0], redD[1]), fmax(redD[2], redD[3]));
  double lsum = 0.0;
  for (int i = tid; i < KK; i += 256) lsum += exp((double)mlogits[i] - (double)gmax);
  #pragma unroll
  for (int o = 32; o > 0; o >>= 1) lsum += __shfl_xor(lsum, o);
  if ((tid & 63) == 0) redD[4 + (tid >> 6)] = lsum;
  __syncthreads();
  if (tid == 0) {
    double lse = (double)gmax + log(redD[4] + redD[5] + redD[6] + redD[7]);
    double b = (double)DD * (log(0.98) + log(1.0 + 2.0 * (0.01 / 0.98)));
    #pragma unroll
    for (int d = 0; d < DD; ++d) b += ws[WS_DIM + d];
    ws[WS_BASE] = b + lse;
  }
}

// =============== kernel B: vor10 + vectorized staging, barrier B removed ===============
#define NT2 1024
#define RPB2 128
#define SL2 8            // sweep-2 slices (128 j)
#define JSL2 (KK / SL2)
#define NS1 16           // sweep-1 slices (64 j)
#define JS1 (KK / NS1)

__global__ __launch_bounds__(NT2, 4) void vor11(
    const float* __restrict__ x_in, const float* __restrict__ logp_in,
    const float* __restrict__ an1_b,
    const float* __restrict__ mlogits, const double* __restrict__ ws,
    const float* __restrict__ aFp, const float* __restrict__ asqHF,
    float* __restrict__ out, int Brows)
{
  __shared__ __align__(16) float sAp[KK][DD];  // 64 KB anchors, pair-permuted
  __shared__ float  sAsqH[KK];                 // 4 KB
  __shared__ double sX4D[DD][RPB2];            // 16 KB f64 x4
  __shared__ float  sLT[DD][RPB2];             // 8 KB lsig terms
  __shared__ double sD2[NS1][RPB2];            // 16 KB refined d2 per (slice16,row)
  __shared__ int    sJJ[NS1][RPB2];            // 8 KB refined j
  __shared__ float  sRat[16][64];              // 4 KB ratio cand per (wave,lane)
  __shared__ float  sOmcF[DD], sB2F[DD], sE2F[DD], sMnF[DD], sMxF[DD];

  const int tid  = threadIdx.x;
  const int w    = tid >> 6;        // 0..15
  const int lane = tid & 63;
  const int rg   = w >> 3;          // sweep-2 row-group
  const int sl   = w & 7;           // sweep-2 slice
  const int rrow = rg * 64 + lane;  // this wave's own row (sweep 2 / epilogue)
  const int r0   = lane, r1 = lane + 64;   // sweep-1 paired rows
  const int row  = blockIdx.x * RPB2 + rrow;
  const size_t coreEnd = (size_t)Brows * (DD + 1);

  if (tid < DD) {
    sOmcF[tid] = (float)ws[WS_OMC + tid];
    sB2F[tid]  = (float)ws[WS_B2 + tid];
    sE2F[tid]  = (float)ws[WS_E2 + tid];
    sMnF[tid]  = (float)ws[WS_MN + tid];
    sMxF[tid]  = (float)ws[WS_MX + tid];
  }
  // stage permuted anchors via float4 copies (precomputed in vor_pre)
  for (int e = tid; e < KK * DD / 4; e += NT2)
    ((float4*)sAp)[e] = ((const float4*)aFp)[e];
  for (int j = tid; j < KK; j += NT2)
    sAsqH[j] = asqHF[j];
  // f64 x4 chain distributed (2 elems/thread)
  {
    const double A = 0.01, EPSB = 0.01 / 0.98;
    const double SPAN = 1.0 + 2.0 * EPSB;
    const float* xb = x_in + (size_t)blockIdx.x * RPB2 * DD;
    for (int e = tid; e < RPB2 * DD; e += NT2) {
      int rr = e >> 4, d = e & 15;
      double y1 = ((double)xb[e] + (double)an1_b[d]) * ws[WS_E1 + d];
      double sg = 1.0 / (1.0 + exp(-y1));
      double x2 = (sg - A) / (1.0 - 2.0 * A);
      double x3 = (x2 + EPSB) / SPAN;
      double x4 = x3 * ws[WS_SCL + d] + ws[WS_MN + d];
      sX4D[d][rr] = x4;
      double ay = fabs(y1);
      sLT[d][rr] = (float)(ay + 2.0 * log1p(exp(-ay)));
    }
  }
  __syncthreads();     // barrier A: sAp, sAsqH, sX4D, sLT ready

  // paired x4 for sweep 1
  f2 xp0[8], xp1[8];
  #pragma unroll
  for (int i = 0; i < 8; ++i) {
    xp0[i] = (f2){(float)sX4D[i][r0], (float)sX4D[i + 8][r0]};
    xp1[i] = (f2){(float)sX4D[i][r1], (float)sX4D[i + 8][r1]};
  }

  // zero this block's f32 mask stripe (drain overlaps sweep 1, proven round 20)
  {
    float4* mz = (float4*)(out + coreEnd + (size_t)blockIdx.x * RPB2 * KK);
    #pragma unroll 4
    for (int i = tid; i < RPB2 * KK / 4; i += NT2)
      mz[i] = make_float4(0.f, 0.f, 0.f, 0.f);
  }

  // ---- sweep 1 (paired pk, 16 slices of 64): top-2 per row ----
  {
    const int jlo = w * JS1, jhi = jlo + JS1;
    float m1_0 = -3.4e38f, m2_0 = -3.4e38f; int j1_0 = jlo, j2_0 = jlo;
    float m1_1 = -3.4e38f, m2_1 = -3.4e38f; int j1_1 = jlo, j2_1 = jlo;
    #pragma unroll 4
    for (int j = jlo; j < jhi; ++j) {
      const float4* ar = (const float4*)&sAp[j][0];
      float4 A0 = ar[0], A1 = ar[1], A2 = ar[2], A3 = ar[3];
      f2 p0 = (f2){A0.x, A0.y}, p1 = (f2){A0.z, A0.w};
      f2 p2 = (f2){A1.x, A1.y}, p3 = (f2){A1.z, A1.w};
      f2 p4 = (f2){A2.x, A2.y}, p5 = (f2){A2.z, A2.w};
      f2 p6 = (f2){A3.x, A3.y}, p7 = (f2){A3.z, A3.w};
      float nq = -sAsqH[j];
      f2 a0 = (f2){nq, 0.f}, a1 = (f2){nq, 0.f};
      a0 = __builtin_elementwise_fma(xp0[0], p0, a0); a1 = __builtin_elementwise_fma(xp1[0], p0, a1);
      a0 = __builtin_elementwise_fma(xp0[1], p1, a0); a1 = __builtin_elementwise_fma(xp1[1], p1, a1);
      a0 = __builtin_elementwise_fma(xp0[2], p2, a0); a1 = __builtin_elementwise_fma(xp1[2], p2, a1);
      a0 = __builtin_elementwise_fma(xp0[3], p3, a0); a1 = __builtin_elementwise_fma(xp1[3], p3, a1);
      a0 = __builtin_elementwise_fma(xp0[4], p4, a0); a1 = __builtin_elementwise_fma(xp1[4], p4, a1);
      a0 = __builtin_elementwise_fma(xp0[5], p5, a0); a1 = __builtin_elementwise_fma(xp1[5], p5, a1);
      a0 = __builtin_elementwise_fma(xp0[6], p6, a0); a1 = __builtin_elementwise_fma(xp1[6], p6, a1);
      a0 = __builtin_elementwise_fma(xp0[7], p7, a0); a1 = __builtin_elementwise_fma(xp1[7], p7, a1);
      float s0 = a0.x + a0.y, s1 = a1.x + a1.y;
      bool g1 = s0 > m1_0, g2 = s0 > m2_0;
      m2_0 = g1 ? m1_0 : (g2 ? s0 : m2_0);
      j2_0 = g1 ? j1_0 : (g2 ? j : j2_0);
      m1_0 = g1 ? s0 : m1_0;
      j1_0 = g1 ? j : j1_0;
      bool h1b = s1 > m1_1, h2b = s1 > m2_1;
      m2_1 = h1b ? m1_1 : (h2b ? s1 : m2_1);
      j2_1 = h1b ? j1_1 : (h2b ? j : j2_1);
      m1_1 = h1b ? s1 : m1_1;
      j1_1 = h1b ? j : j1_1;
    }
    // f64 refine both rows' top-2
    {
      double bD = 1e300; int bk = 0x7fffffff;
      #pragma unroll
      for (int t = 0; t < 2; ++t) {
        int j = t ? j2_0 : j1_0;
        const double* aj = ws + WS_A + (size_t)j * DD;
        double dot = 0.0;
        #pragma unroll
        for (int d = 0; d < DD; ++d) dot = fma(sX4D[d][r0], aj[d], dot);
        double d2 = ws[WS_ASQ + j] - 2.0 * dot;
        if (d2 < bD || (d2 == bD && j < bk)) { bD = d2; bk = j; }
      }
      sD2[w][r0] = bD; sJJ[w][r0] = bk;
    }
    {
      double bD = 1e300; int bk = 0x7fffffff;
      #pragma unroll
      for (int t = 0; t < 2; ++t) {
        int j = t ? j2_1 : j1_1;
        const double* aj = ws + WS_A + (size_t)j * DD;
        double dot = 0.0;
        #pragma unroll
        for (int d = 0; d < DD; ++d) dot = fma(sX4D[d][r1], aj[d], dot);
        double d2 = ws[WS_ASQ + j] - 2.0 * dot;
        if (d2 < bD || (d2 == bD && j < bk)) { bD = d2; bk = j; }
      }
      sD2[w][r1] = bD; sJJ[w][r1] = bk;
    }
  }
  __syncthreads();     // barrier C: drains mask stores (overlapped with sweep 1)

  // combine k for OWN row across 16 slices (deterministic)
  int k = 0x7fffffff;
  {
    double kb = 1e300;
    #pragma unroll
    for (int ss = 0; ss < NS1; ++ss) {
      double d = sD2[ss][rrow];
      int    j = sJJ[ss][rrow];
      if (d < kb || (d == kb && j < k)) { kb = d; k = j; }
    }
  }

  // ---- sweep 2 setup (own row) ----
  float x4f[DD];
  #pragma unroll
  for (int d = 0; d < DD; ++d) x4f[d] = (float)sX4D[d][rrow];
  float akf[DD];
  {
    const float4* akp = (const float4*)&sAp[k][0];
    float4 K0 = akp[0], K1 = akp[1], K2 = akp[2], K3 = akp[3];
    akf[0] = K0.x; akf[8]  = K0.y; akf[1] = K0.z; akf[9]  = K0.w;
    akf[2] = K1.x; akf[10] = K1.y; akf[3] = K1.z; akf[11] = K1.w;
    akf[4] = K2.x; akf[12] = K2.y; akf[5] = K2.z; akf[13] = K2.w;
    akf[6] = K3.x; akf[14] = K3.y; akf[7] = K3.z; akf[15] = K3.w;
  }
  float dxf[DD];
  float r2f = 0.f, dxak = 0.f;
  #pragma unroll
  for (int d = 0; d < DD; ++d) {
    float dx = sOmcF[d] * (x4f[d] - akf[d]);
    dxf[d] = dx;
    r2f  = fmaf(dx, dx, r2f);
    dxak = fmaf(dx, akf[d], dxak);
  }
  const float rf   = sqrtf(r2f);
  const float rrf  = fmaxf(rf, 1e-12f);
  const float scal = rf / rrf;
  const float epsr = 1e-12f * rf;
  const float asqhk = sAsqH[k];

  f2 dx2[8], nak2[8];
  #pragma unroll
  for (int i = 0; i < 8; ++i) {
    dx2[i]  = (f2){dxf[i], dxf[i + 8]};
    nak2[i] = (f2){-akf[i], -akf[i + 8]};
  }

  // ---- sweep 2 (pk f32, 8 slices of 128) ----
  float q1 = 0.f, h1 = 1.f;
  const int jlo2 = sl * JSL2, jhi2 = jlo2 + JSL2;
  #pragma unroll 4
  for (int j = jlo2; j < jhi2; ++j) {
    const float4* ar = (const float4*)&sAp[j][0];
    float4 A0 = ar[0], A1 = ar[1], A2 = ar[2], A3 = ar[3];
    f2 p0 = (f2){A0.x, A0.y}, p1 = (f2){A0.z, A0.w};
    f2 p2 = (f2){A1.x, A1.y}, p3 = (f2){A1.z, A1.w};
    f2 p4 = (f2){A2.x, A2.y}, p5 = (f2){A2.z, A2.w};
    f2 p6 = (f2){A3.x, A3.y}, p7 = (f2){A3.z, A3.w};
    f2 q2 = (f2){-dxak, 0.f};
    f2 h2 = (f2){asqhk + sAsqH[j], 0.f};
    q2 = __builtin_elementwise_fma(dx2[0], p0, q2); h2 = __builtin_elementwise_fma(nak2[0], p0, h2);
    q2 = __builtin_elementwise_fma(dx2[1], p1, q2); h2 = __builtin_elementwise_fma(nak2[1], p1, h2);
    q2 = __builtin_elementwise_fma(dx2[2], p2, q2); h2 = __builtin_elementwise_fma(nak2[2], p2, h2);
    q2 = __builtin_elementwise_fma(dx2[3], p3, q2); h2 = __builtin_elementwise_fma(nak2[3], p3, h2);
    q2 = __builtin_elementwise_fma(dx2[4], p4, q2); h2 = __builtin_elementwise_fma(nak2[4], p4, h2);
    q2 = __builtin_elementwise_fma(dx2[5], p5, q2); h2 = __builtin_elementwise_fma(nak2[5], p5, h2);
    q2 = __builtin_elementwise_fma(dx2[6], p6, q2); h2 = __builtin_elementwise_fma(nak2[6], p6, h2);
    q2 = __builtin_elementwise_fma(dx2[7], p7, q2); h2 = __builtin_elementwise_fma(nak2[7], p7, h2);
    float q = q2.x + q2.y, h = h2.x + h2.y;
    bool upd = (j != k) & (q > epsr) & (q * h1 > q1 * h);
    q1 = upd ? q : q1;
    h1 = upd ? h : h1;
  }
  sRat[w][lane] = scal * (q1 / h1);
  __syncthreads();     // barrier D

  // ---- epilogue waves (sl==0, one per rg): combine ratio, box faces, outputs ----
  if (sl == 0) {
    float ratio = rf * 1e-9f;
    #pragma unroll
    for (int ss = 0; ss < SL2; ++ss) ratio = fmaxf(ratio, sRat[rg * 8 + ss][lane]);
    #pragma unroll
    for (int d = 0; d < DD; ++d) {
      float uf = dxf[d] / rrf;
      if (uf > 1e-12f)        ratio = fmaxf(ratio, rf * uf / (sMxF[d] - akf[d]));
      else if (uf < -1e-12f)  ratio = fmaxf(ratio, rf * uf / (sMnF[d] - akf[d]));
    }
    float sS = 1.0f / (1.0f - ratio);
    float xo[DD];
    float lsig = 0.f;
    #pragma unroll
    for (int d = 0; d < DD; ++d) {
      xo[d] = (dxf[d] * sS + sB2F[d]) * sE2F[d];
      lsig += sLT[d][rrow];
    }
    float4* xp = (float4*)(out + (size_t)row * DD);
    xp[0] = make_float4(xo[0], xo[1], xo[2], xo[3]);
    xp[1] = make_float4(xo[4], xo[5], xo[6], xo[7]);
    xp[2] = make_float4(xo[8], xo[9], xo[10], xo[11]);
    xp[3] = make_float4(xo[12], xo[13], xo[14], xo[15]);
    double lp = (double)logp_in[row] + ws[WS_BASE] + (double)lsig
              + 17.0 * log1p(-(double)ratio)
              - (double)mlogits[k];
    out[(size_t)Brows * DD + row] = (float)lp;
    out[coreEnd + (size_t)row * KK + k] = 1.0f;
  }
}

// =============== fallback: round-6 green kernel (unchanged) ===============
#define NT 256
#define RPB 64
#define SLC4 4
#define JSL4 (KK / SLC4)

__global__ __launch_bounds__(NT, 2) void vor_green(
    const float* __restrict__ x_in, const float* __restrict__ logp_in,
    const float* __restrict__ an1_w, const float* __restrict__ an1_b,
    const float* __restrict__ an2_w, const float* __restrict__ an2_b,
    const float* __restrict__ shift_c, const float* __restrict__ anchor_raw,
    const float* __restrict__ box_min, const float* __restrict__ box_max,
    const float* __restrict__ mlogits,
    float* __restrict__ out, int Brows)
{
  __shared__ __align__(16) float sA[KK][DD];
  __shared__ float  sAsqH[KK];
  __shared__ float  sX4T[DD][RPB];
  __shared__ int    sPj1[SLC4][RPB], sPj2[SLC4][RPB];
  __shared__ int    sRI1[SLC4][RPB], sRI2[SLC4][RPB];
  __shared__ double sPartD[8];
  __shared__ double sE1D[DD], sB1D[DD], sOmcD[DD], sB2D[DD], sE2D[DD];
  __shared__ double sMnD[DD], sMxD[DD], sSclD[DD], sDimD[DD];
  __shared__ double sBaseD;
  __shared__ int    sKidx[RPB];

  const int tid  = threadIdx.x;
  const int sl   = tid >> 6;
  const int lane = tid & 63;
  const int row  = blockIdx.x * RPB + lane;
  const size_t coreEnd = (size_t)Brows * (DD + 1);

  for (int e = tid; e < KK * DD / 4; e += NT) {
    float4 raw = ((const float4*)anchor_raw)[e];
    float4 bmn = ((const float4*)box_min)[e & 3];
    float4 bmx = ((const float4*)box_max)[e & 3];
    float4 o;
    o.x = xformF(raw.x, bmn.x, bmx.x);
    o.y = xformF(raw.y, bmn.y, bmx.y);
    o.z = xformF(raw.z, bmn.z, bmx.z);
    o.w = xformF(raw.w, bmn.w, bmx.w);
    ((float4*)sA)[e] = o;
  }
  if (tid < DD) {
    double w1 = (double)an1_w[tid];
    sE1D[tid] = exp(w1);
    sB1D[tid] = (double)an1_b[tid];
    double sgc = 1.0 / (1.0 + exp(-(double)shift_c[tid]));
    double c = sgc * 0.98 + 0.01;
    sOmcD[tid] = 1.0 - c;
    double mn = (double)box_min[tid], mx = (double)box_max[tid];
    sMnD[tid] = mn; sMxD[tid] = mx; sSclD[tid] = mx - mn;
    double w2 = (double)an2_w[tid];
    sE2D[tid] = exp(w2);
    sB2D[tid] = (double)an2_b[tid];
    sDimD[tid] = -w1 - log(mx - mn) - log1p(-c) - w2;
  }
  __syncthreads();

  for (int j = tid; j < KK; j += NT) {
    float acc = 0.f;
    #pragma unroll
    for (int d = 0; d < DD; ++d) { float a = sA[j][d]; acc = fmaf(a, a, acc); }
    sAsqH[j] = 0.5f * acc;
  }

  float lm = -3.4e38f;
  for (int i = tid; i < KK; i += NT) lm = fmaxf(lm, mlogits[i]);
  #pragma unroll
  for (int o = 32; o > 0; o >>= 1) lm = fmaxf(lm, __shfl_xor(lm, o));
  if (lane == 0) sPartD[sl] = (double)lm;
  __syncthreads();
  float gmax = (float)fmax(fmax(sPartD[0], sPartD[1]), fmax(sPartD[2], sPartD[3]));
  double lsum = 0.0;
  for (int i = tid; i < KK; i += NT) lsum += exp((double)mlogits[i] - (double)gmax);
  #pragma unroll
  for (int o = 32; o > 0; o >>= 1) lsum += __shfl_xor(lsum, o);
  if (lane == 0) sPartD[4 + sl] = lsum;
  __syncthreads();
  if (tid == 0) {
    double lse = (double)gmax + log(sPartD[4] + sPartD[5] + sPartD[6] + sPartD[7]);
    double b = (double)DD * (log(0.98) + log(1.0 + 2.0 * (0.01 / 0.98)));
    #pragma unroll
    for (int d = 0; d < DD; ++d) b += sDimD[d];
    sBaseD = b + lse;
  }

  double x4d[DD];
  double lsigD = 0.0;
  if (sl == 0) {
    const double A = 0.01, EPSB = 0.01 / 0.98;
    const double SPAN = 1.0 + 2.0 * EPSB;
    const float* xr = x_in + (size_t)row * DD;
    #pragma unroll
    for (int d = 0; d < DD; ++d) {
      double y1 = ((double)xr[d] + sB1D[d]) * sE1D[d];
      double sg = 1.0 / (1.0 + exp(-y1));
      double x2 = (sg - A) / (1.0 - 2.0 * A);
      double x3 = (x2 + EPSB) / SPAN;
      double x4 = x3 * sSclD[d] + sMnD[d];
      x4d[d] = x4;
      sX4T[d][lane] = (float)x4;
      double ay = fabs(y1);
      lsigD += ay + 2.0 * log1p(exp(-ay));
    }
  }
  {
    float4* mz = (float4*)(out + coreEnd + (size_t)blockIdx.x * RPB * KK);
    #pragma unroll 4
    for (int i = tid; i < RPB * KK / 4; i += NT)
      mz[i] = make_float4(0.f, 0.f, 0.f, 0.f);
  }
  __syncthreads();

  float x4f[DD];
  #pragma unroll
  for (int d = 0; d < DD; ++d) x4f[d] = sX4T[d][lane];

  float m1 = -3.4e38f, m2v = -3.4e38f;
  int j1 = 0x7fffffff, j2v = 0x7fffffff;
  const int jlo = sl * JSL4, jhi = jlo + JSL4;
  #pragma unroll 2
  for (int j = jlo; j < jhi; ++j) {
    float acc = -sAsqH[j];
    const float4* ar = (const float4*)&sA[j][0];
    #pragma unroll
    for (int dq = 0; dq < 4; ++dq) {
      float4 a4 = ar[dq];
      acc = fmaf(x4f[4 * dq + 0], a4.x, acc);
      acc = fmaf(x4f[4 * dq + 1], a4.y, acc);
      acc = fmaf(x4f[4 * dq + 2], a4.z, acc);
      acc = fmaf(x4f[4 * dq + 3], a4.w, acc);
    }
    bool gt1 = acc > m1;
    bool gt2 = acc > m2v;
    m2v = gt1 ? m1 : (gt2 ? acc : m2v);
    j2v = gt1 ? j1 : (gt2 ? j : j2v);
    m1  = gt1 ? acc : m1;
    j1  = gt1 ? j : j1;
  }
  sPj1[sl][lane] = j1;
  sPj2[sl][lane] = j2v;
  __syncthreads();

  if (sl == 0) {
    double best = 1e300; int bk = 0x7fffffff;
    #pragma unroll
    for (int ss = 0; ss < SLC4; ++ss) {
      #pragma unroll
      for (int t = 0; t < 2; ++t) {
        int j = t ? sPj2[ss][lane] : sPj1[ss][lane];
        double asq = 0.0, dot = 0.0;
        #pragma unroll
        for (int d = 0; d < DD; ++d) {
          double a = xformD((double)anchor_raw[j * DD + d], sMnD[d], sSclD[d]);
          asq = fma(a, a, asq);
          dot = fma(x4d[d], a, dot);
        }
        double d2 = asq - 2.0 * dot;
        if (d2 < best || (d2 == best && j < bk)) { best = d2; bk = j; }
      }
    }
    sKidx[lane] = bk;
  }
  __syncthreads();

  const int k = sKidx[lane];

  float akf[DD], dxf[DD];
  float r2f = 0.f, dxak = 0.f;
  #pragma unroll
  for (int d = 0; d < DD; ++d) {
    float a = sA[k][d];
    akf[d] = a;
    float dx = (float)sOmcD[d] * (x4f[d] - a);
    dxf[d] = dx;
    r2f  = fmaf(dx, dx, r2f);
    dxak = fmaf(dx, a, dxak);
  }
  const float epsr = 1e-12f * sqrtf(r2f);
  const float asqhk = sAsqH[k];

  float q1 = 0.f, h1 = 1.f, q2 = 0.f, h2 = 1.f;
  int i1 = -1, i2 = -1;
  #pragma unroll 2
  for (int j = jlo; j < jhi; ++j) {
    float q = -dxak;
    float h = asqhk + sAsqH[j];
    const float4* ar = (const float4*)&sA[j][0];
    #pragma unroll
    for (int dq = 0; dq < 4; ++dq) {
      float4 a4 = ar[dq];
      q = fmaf(dxf[4 * dq + 0], a4.x, q);
      q = fmaf(dxf[4 * dq + 1], a4.y, q);
      q = fmaf(dxf[4 * dq + 2], a4.z, q);
      q = fmaf(dxf[4 * dq + 3], a4.w, q);
      h = fmaf(-akf[4 * dq + 0], a4.x, h);
      h = fmaf(-akf[4 * dq + 1], a4.y, h);
      h = fmaf(-akf[4 * dq + 2], a4.z, h);
      h = fmaf(-akf[4 * dq + 3], a4.w, h);
    }
    bool valid = (j != k) & (q > epsr);
    bool b1 = valid && (q * h1 > q1 * h);
    bool b2 = valid && (q * h2 > q2 * h);
    float nq2 = b1 ? q1 : (b2 ? q : q2);
    float nh2 = b1 ? h1 : (b2 ? h : h2);
    int   ni2 = b1 ? i1 : (b2 ? j : i2);
    q1 = b1 ? q : q1; h1 = b1 ? h : h1; i1 = b1 ? j : i1;
    q2 = nq2; h2 = nh2; i2 = ni2;
  }
  sRI1[sl][lane] = i1;
  sRI2[sl][lane] = i2;
  __syncthreads();

  if (sl == 0) {
    double akD[DD], dxD[DD];
    double r2 = 0.0;
    #pragma unroll
    for (int d = 0; d < DD; ++d) {
      double a = xformD((double)anchor_raw[k * DD + d], sMnD[d], sSclD[d]);
      akD[d] = a;
      double dx = sOmcD[d] * (x4d[d] - a);
      dxD[d] = dx;
      r2 = fma(dx, dx, r2);
    }
    double rD = sqrt(r2);
    double rr = fmax(rD, 1e-12);
    double ratio = rD / 1e9;

    #pragma unroll
    for (int ss = 0; ss < SLC4; ++ss) {
      #pragma unroll
      for (int t = 0; t < 2; ++t) {
        int j = t ? sRI2[ss][lane] : sRI1[ss][lane];
        if (j < 0 || j == k) continue;
        double q = 0.0, h = 0.0;
        #pragma unroll
        for (int d = 0; d < DD; ++d) {
          double aj = xformD((double)anchor_raw[j * DD + d], sMnD[d], sSclD[d]);
          double g = aj - akD[d];
          q = fma(dxD[d], g, q);
          h = fma(g, g, h);
        }
        double proj = q / rr;
        if (proj > 1e-12) {
          double cand = rD * proj / (0.5 * h);
          ratio = fmax(ratio, cand);
        }
      }
    }
    #pragma unroll
    for (int d = 0; d < DD; ++d) {
      double u = dxD[d] / rr;
      if (u > 1e-12)        ratio = fmax(ratio, rD * u / (sMxD[d] - akD[d]));
      else if (u < -1e-12)  ratio = fmax(ratio, rD * u / (sMnD[d] - akD[d]));
    }

    double sS = 1.0 / (1.0 - ratio);
    float* xo = out + (size_t)row * DD;
    #pragma unroll
    for (int d = 0; d < DD; ++d) {
      double x7 = dxD[d] * sS;
      double x8 = (x7 + sB2D[d]) * sE2D[d];
      xo[d] = (float)x8;
    }
    double lp = (double)logp_in[row] + sBaseD + lsigD
              + 17.0 * log1p(-ratio)
              - (double)mlogits[k];
    out[(size_t)Brows * DD + row] = (float)lp;
    out[coreEnd + (size_t)row * KK + k] = 1.0f;
  }
}

extern "C" void kernel_launch(void* const* d_in, const int* in_sizes, int n_in,
                              void* d_out, int out_size, void* d_ws, size_t ws_size,
                              hipStream_t stream) {
  (void)n_in; (void)out_size;
  const float* x_in   = (const float*)d_in[0];
  const float* logp   = (const float*)d_in[1];
  const float* an1w   = (const float*)d_in[2];
  const float* an1b   = (const float*)d_in[3];
  const float* an2w   = (const float*)d_in[4];
  const float* an2b   = (const float*)d_in[5];
  const float* shiftc = (const float*)d_in[6];
  const float* anchor = (const float*)d_in[7];
  const float* bmin   = (const float*)d_in[8];
  const float* bmax   = (const float*)d_in[9];
  const float* mlog   = (const float*)d_in[10];
  const int B = in_sizes[0] / DD;

  if (ws_size >= (size_t)WS_NEED_BYTES && d_ws != nullptr && (B % RPB2) == 0) {
    double* ws = (double*)d_ws;
    const float* aFp   = (const float*)(ws + WS_AFP);
    const float* asqHF = (const float*)(ws + WS_ASQF);
    hipLaunchKernelGGL(vor_pre, dim3(16), dim3(256), 0, stream,
                       an1w, an2w, an2b, shiftc, anchor, bmin, bmax, mlog, ws);
    hipLaunchKernelGGL(vor11, dim3(B / RPB2), dim3(NT2), 0, stream,
                       x_in, logp, an1b, mlog, (const double*)ws,
                       aFp, asqHF, (float*)d_out, B);
  } else {
    hipLaunchKernelGGL(vor_green, dim3(B / RPB), dim3(NT), 0, stream,
                       x_in, logp, an1w, an1b, an2w, an2b, shiftc, anchor,
                       bmin, bmax, mlog, (float*)d_out, B);
  }
}